// Round 10
// baseline (211.797 us; speedup 1.0000x reference)
//
#include <hip/hip_runtime.h>
#include <math.h>

#ifndef M_PI
#define M_PI 3.14159265358979323846
#endif

#define BB 8
#define NN 512
#define KK 64
#define GG 4096
#define MM 100

// ---------------- workspace layout (byte offsets) ----------------
// vd / vm / ad are fp32 (selection is fp32-exact; inversion is fp32)
#define SZ_VD    (BB*GG*4u)
#define OFF_VD   0u
#define SZ_VM    (BB*MM*4u)
#define OFF_VM   (OFF_VD + SZ_VD)
#define SZ_AD    (BB*MM*MM*4u)
#define OFF_AD   (OFF_VM + SZ_VM)

// ---------------- output layout (float element offsets) ----------------
#define OUT_M  0
#define OUT_V  (BB*NN*GG)               // 16,777,216
#define OUT_A  (OUT_V + BB*GG)          // 16,809,984
#define OUT_B  (OUT_A + BB*MM*MM)      // 16,889,984
#define OUT_MI (OUT_B + BB*MM*MM)      // 16,969,984

// ---------------- m-unit allocation across dispatches ----------------
// r10 change: GRID-STRIDE m-blocks. Each m-block handles MU_PER=8 units
// (one unit = 256 thr x float4 = 4 KB). 8x fewer block launches (r9 had
// 40 sequential 1-unit blocks per CU in k_inv_m -> block-churn tail) and
// 8 independent stores in flight per thread.
#define MU_PER 8
#define MU_VP 4096            // with k_vpart   (units 0..4095)       -> 512 blocks
#define MU_AS 2048            // with k_Asel    (units 4096..6143)    -> 256 blocks
#define MU_IV 10240           // with k_inv_m   (units 6144..16383)   -> 1280 blocks

__device__ __forceinline__ void m_units(const float* __restrict__ pts,
                                        float* __restrict__ out, int u0, int cnt) {
  const float CM = (float)(1.0/(2.0*M_PI*128.0));
  for (int k = 0; k < cnt; ++k) {
    int u = u0 + k;
    int t = u*256 + (int)threadIdx.x;
    int e = t << 2;
    int img = e >> 21;
    int rem = e & ((1 << 21) - 1);
    int n = rem >> 12;
    int g = rem & 4095;
    int iy = g >> 6, ix = g & 63;       // e%4==0 -> ix%4==0
    float x = pts[(img*NN + n)*2 + 0];
    float y = pts[(img*NN + n)*2 + 1];
    float dy = y - (8.0f*iy + 4.0f);
    float ey = __expf(dy*dy*(-0.5f/128.0f));
    float4 r;
    float dx0 = x - (8.0f*ix + 4.0f);
    float dx1 = x - (8.0f*(ix+1) + 4.0f);
    float dx2 = x - (8.0f*(ix+2) + 4.0f);
    float dx3 = x - (8.0f*(ix+3) + 4.0f);
    r.x = ey*__expf(dx0*dx0*(-0.5f/128.0f))*CM;
    r.y = ey*__expf(dx1*dx1*(-0.5f/128.0f))*CM;
    r.z = ey*__expf(dx2*dx2*(-0.5f/128.0f))*CM;
    r.w = ey*__expf(dx3*dx3*(-0.5f/128.0f))*CM;
    *reinterpret_cast<float4*>(&out[OUT_M + e]) = r;
  }
}

__device__ __forceinline__ float flt_readlane(float v, int l) {
  return __int_as_float(__builtin_amdgcn_readlane(__float_as_int(v), l));
}

// ============ K2: v — two 64x64 matmuls (fp64 accum, fp32 store) + m blocks ============
__global__ __launch_bounds__(256) void k_vpart(const float* __restrict__ pts,
                                               float* __restrict__ vd,
                                               float* __restrict__ out) {
  __shared__ double sEy2[16][66], sEx2[16][66], sEy3[16][66], sEx3[16][66];
  __shared__ float px[NN], py[NN];
  int bid = blockIdx.x;                 // img*16 + tile  |  m blocks
  if (bid >= BB*16) { m_units(pts, out, (bid - BB*16)*MU_PER, MU_PER); return; }
  int tile = bid & 15;
  int img = bid >> 4;
  int iy0 = (tile >> 2) << 4;
  int ix0 = (tile & 3) << 4;
  int tx = threadIdx.x & 15, ty = threadIdx.x >> 4;
  for (int s = threadIdx.x; s < NN; s += 256) {
    px[s] = pts[(img*NN + s)*2 + 0];
    py[s] = pts[(img*NN + s)*2 + 1];
  }
  double aV = 0.0, aM = 0.0;
  for (int kc = 0; kc < 8; ++kc) {
    int nb = kc << 6;
    __syncthreads();                    // WAR on LDS (and px/py ready on kc=0)
    for (int s = threadIdx.x; s < 16*64; s += 256) {
      int row = s >> 6, n = s & 63;
      int nn = nb + n;
      double y = (double)py[nn];
      double cy = 8.0*(iy0 + row) + 4.0;
      double dy = y - cy, dy2 = dy*dy;
      sEy2[row][n] = exp(dy2*(-0.5/96.0));
      sEy3[row][n] = exp(dy2*(-1.0/128.0));
      double x = (double)px[nn];
      double cx = 8.0*(ix0 + row) + 4.0;
      double dx = x - cx, dx2 = dx*dx;
      sEx2[row][n] = exp(dx2*(-0.5/96.0));
      sEx3[row][n] = exp(dx2*(-1.0/128.0));
    }
    __syncthreads();
    #pragma unroll 8
    for (int n = 0; n < 64; ++n) {
      aV += sEy2[ty][n]*sEx2[tx][n];
      aM += sEy3[ty][n]*sEx3[tx][n];
    }
  }
  const double CTV = 1.0/((2.0*M_PI*96.0)*(2.0*M_PI*128.0));
  const double CM2 = 1.0/((2.0*M_PI*128.0)*(2.0*M_PI*128.0));
  vd[img*GG + (iy0 + ty)*KK + ix0 + tx] = (float)(CTV*aV - CM2*aM);
}

// ---------------- LDS union for fused select+A ----------------
union AselU {
  struct {
    unsigned int ku[GG];                       // 16 KB fp32 sortable keys
    unsigned int hist4[4][256];                // per-wave histogram copies
    unsigned int wq[4];                        // wave totals for suffix scan
    unsigned int sPref, sMask;
    unsigned int sRem, sPickB, sPickRem, sCGt, sCEq;
    int tie[128];
  } se;                                        // ~21 KB
  struct {
    float sxi[16][130], syi[16][130], sti[16][130];
    float sxj[16][130], syj[16][130], stj[16][130];
    float px[NN], py[NN];
    float cxi[16], cyi[16], cxj[16], cyj[16];
  } ka;                                        // 54,272 B (max)
};

// ---------------- bitonic sort of 128 ints ascending (shared array) ----------------
__device__ __forceinline__ void bitonic128(int* a, int tid) {
  for (int kk = 2; kk <= 128; kk <<= 1)
    for (int jj = kk >> 1; jj > 0; jj >>= 1) {
      if (tid < 128) {
        int p = tid ^ jj;
        if (p > tid) {
          int x = a[tid], y = a[p];
          bool up = ((tid & kk) == 0);
          if (up ? (x > y) : (x < y)) { a[tid] = y; a[p] = x; }
        }
      }
      __syncthreads();
    }
}

// ============ K34: FUSED fp32 top-100 radix select + A assembly + m blocks ============
__global__ __launch_bounds__(256) void k_Asel(const float* __restrict__ pts,
                                              const float* __restrict__ vd,
                                              float* __restrict__ out,
                                              float* __restrict__ ad,
                                              float* __restrict__ vm) {
  __shared__ AselU u;
  __shared__ int selFinal[128];         // survives the union switch se -> ka
  int bid = blockIdx.x;                 // img*28 + tri-tile  |  m blocks
  if (bid >= BB*28) { m_units(pts, out, MU_VP + (bid - BB*28)*MU_PER, MU_PER); return; }
  int img = bid / 28;
  int tile = bid - img*28;
  bool tile0 = (tile == 0);
  int tid = threadIdx.x;
  int wv = tid >> 6;
  int lane = tid & 63;

  // ================= select phase (LDS as u.se) =================
  for (int t = 0; t < 16; ++t) {
    int g = t*256 + tid;
    float v = vd[img*GG + g];
    if (tile0) out[OUT_V + img*GG + g] = fmaxf(v, 1e-6f);
    int w = __float_as_int(v);
    u.se.ku[g] = (w < 0) ? ~(unsigned)w : ((unsigned)w | 0x80000000u);
  }
  if (tid == 0) {
    u.se.sRem = 100; u.se.sPref = 0u; u.se.sMask = 0u;
    u.se.sCGt = 0; u.se.sCEq = 0;
  }
  // ---- 4 radix passes, MSB first ----
  for (int shift = 24; shift >= 0; shift -= 8) {
    for (int c = 0; c < 4; ++c) u.se.hist4[c][tid] = 0;
    __syncthreads();                    // ku/state ready, hist zeroed
    unsigned mask = u.se.sMask, pref = u.se.sPref;
    for (int t = 0; t < 16; ++t) {
      unsigned k = u.se.ku[t*256 + tid];
      if ((k & mask) == pref)
        atomicAdd(&u.se.hist4[wv][(k >> shift) & 255u], 1u);
    }
    __syncthreads();
    unsigned tot = u.se.hist4[0][tid] + u.se.hist4[1][tid]
                 + u.se.hist4[2][tid] + u.se.hist4[3][tid];
    // wave-level inclusive SUFFIX scan over the 64 bins this wave owns
    unsigned val = tot;
    #pragma unroll
    for (int off = 1; off < 64; off <<= 1) {
      unsigned o = (unsigned)__shfl_down((int)val, off);
      if (lane + off < 64) val += o;
    }
    if (lane == 0) u.se.wq[wv] = val;   // whole-wave total
    __syncthreads();
    unsigned suf = val;                 // + totals of higher waves (higher digits)
    for (int w2 = wv + 1; w2 < 4; ++w2) suf += u.se.wq[w2];
    unsigned rem = u.se.sRem;
    unsigned sgt = suf - tot;           // count with digit strictly greater
    if (suf >= rem && sgt < rem) { u.se.sPickB = (unsigned)tid; u.se.sPickRem = rem - sgt; }
    __syncthreads();
    if (tid == 0) {
      u.se.sPref |= u.se.sPickB << shift;
      u.se.sMask |= 255u << shift;
      u.se.sRem   = u.se.sPickRem;
    }
    __syncthreads();
  }
  // ---- collect: all k > T, plus r smallest-index ties (k == T) ----
  unsigned T = u.se.sPref;              // exact 100th-largest fp32 key
  for (int t = 0; t < 16; ++t) {
    int g = t*256 + tid;
    unsigned k = u.se.ku[g];
    if (k > T) {
      unsigned p = atomicAdd(&u.se.sCGt, 1u);   // p <= 98 always
      selFinal[p] = g;
    } else if (k == T) {
      unsigned p = atomicAdd(&u.se.sCEq, 1u);
      if (p < 128) u.se.tie[p] = g;     // >128 exact-equal boundary: pathological
    }
  }
  __syncthreads();
  unsigned cgt = u.se.sCGt, ceq = u.se.sCEq, r = u.se.sRem;
  if (tid < 128 && tid >= (int)((ceq < 128u) ? ceq : 128u)) u.se.tie[tid] = 0x7fffffff;
  __syncthreads();
  bitonic128(u.se.tie, tid);                     // ties ascending by index
  if (tid < (int)r) selFinal[cgt + tid] = u.se.tie[tid];
  if (tid >= MM && tid < 128) selFinal[tid] = 0x7fffffff;
  __syncthreads();
  bitonic128(selFinal, tid);                     // final Minds ascending
  if (tile0 && tid < MM) {
    int mi = selFinal[tid];
    out[OUT_MI + img*MM + tid] = (float)mi;      // whole out buffer is float32
    vm[img*MM + tid] = fmaxf(vd[img*GG + mi], 1e-6f) + 1e-10f;  // ref fp32 semantics
  }
  __syncthreads();                               // done with u.se before ka overwrite

  // ================= A phase (LDS as u.ka) =================
  int it = 0, trem = tile;
  while (trem >= 7 - it) { trem -= 7 - it; ++it; }
  int jt = it + trem;
  int i0 = it*16, j0 = jt*16;
  int tj = tid & 15, ti = tid >> 4;
  int i = i0 + ti, j = j0 + tj;
  const float CM = (float)(1.0/(2.0*M_PI*128.0));
  const float C1 = (float)(1.0/(2.0*M_PI*128.0));   // g1 scale (2*pi*2*sigma2)
  const float C2 = (float)(1.0/(2.0*M_PI*96.0));    // h scale (2*pi*s2)
  for (int s = tid; s < NN; s += 256) {
    u.ka.px[s] = pts[(img*NN + s)*2 + 0];
    u.ka.py[s] = pts[(img*NN + s)*2 + 1];
  }
  if (tid < 16) {
    int gi = i0 + tid; if (gi > 99) gi = 99;
    int mi = selFinal[gi];
    u.ka.cxi[tid] = 8.0f*(mi & 63) + 4.0f;
    u.ka.cyi[tid] = 8.0f*(mi >> 6) + 4.0f;
  } else if (tid < 32) {
    int rr = tid - 16;
    int gj = j0 + rr; if (gj > 99) gj = 99;
    int mj = selFinal[gj];
    u.ka.cxj[rr] = 8.0f*(mj & 63) + 4.0f;
    u.ka.cyj[rr] = 8.0f*(mj >> 6) + 4.0f;
  }
  float aV = 0.0f, aM = 0.0f;
  for (int nc = 0; nc < NN; nc += 128) {
    __syncthreads();
    for (int s = tid; s < 16*128; s += 256) {
      int row = s >> 7, n = s & 127;
      float x = u.ka.px[nc + n], y = u.ka.py[nc + n];
      float fxi = x - u.ka.cxi[row], fyi = y - u.ka.cyi[row];
      u.ka.sxi[row][n] = fxi; u.ka.syi[row][n] = fyi;
      u.ka.sti[row][n] = __expf((fxi*fxi + fyi*fyi)*(-0.5f/128.0f))*CM;
      float fxj = x - u.ka.cxj[row], fyj = y - u.ka.cyj[row];
      u.ka.sxj[row][n] = fxj; u.ka.syj[row][n] = fyj;
      u.ka.stj[row][n] = __expf((fxj*fxj + fyj*fyj)*(-0.5f/128.0f))*CM;
    }
    __syncthreads();
    #pragma unroll 4
    for (int n = 0; n < 128; ++n) {
      float xi = u.ka.sxi[ti][n], yi = u.ka.syi[ti][n], tii = u.ka.sti[ti][n];
      float xj = u.ka.sxj[tj][n], yj = u.ka.syj[tj][n], tjj = u.ka.stj[tj][n];
      float ddx = xj - xi, ddy = yj - yi;
      float df = ddx*ddx + ddy*ddy;
      float sx = 0.5f*(xi + xj), sy = 0.5f*(yi + yj);
      float af = sx*sx + sy*sy;
      float g1 = __expf(df*(-0.5f/128.0f))*C1;
      float h  = __expf(af*(-0.5f/96.0f))*C2;
      aV += g1 + g1*h;
      aM += tii*tjj;
    }
  }
  if (i < 100 && j < 100) {
    float val = (i == j) ? 1e-10f : (float)((double)aV - (double)aM);
    out[OUT_A + (img*MM + i)*MM + j] = val;
    ad[(img*MM + i)*MM + j] = val;
    if (it != jt) {                     // mirror (diag tiles cover both in-tile)
      out[OUT_A + (img*MM + j)*MM + i] = val;
      ad[(img*MM + j)*MM + i] = val;
    }
  }
}

// ============ K5: FP32 GJ inversion (blocks 0..7) + remaining m blocks ============
__global__ __launch_bounds__(256)
void k_inv_m(const float* __restrict__ ad,
             const float* __restrict__ vm,
             const float* __restrict__ pts,
             float* __restrict__ out) {
  __shared__ float S[128*17];           //  8,704 B
  __shared__ float Pr[16*113];          //  7,232 B
  __shared__ float svm[112];            //    448 B  -> total 16,384 B
  if (blockIdx.x >= BB) {
    m_units(pts, out, MU_VP + MU_AS + ((int)blockIdx.x - BB)*MU_PER, MU_PER);
    return;
  }
  // ---- inversion part: no-pivot blocked fp32 GJ (SPD), Bm = Dv^{-1} - (A+Dv)^{-1}
  int img = blockIdx.x;
  int tx = threadIdx.x & 15, ty = threadIdx.x >> 4;   // ty in [0,16)
  float C[7][7];
  if (threadIdx.x < 100) svm[threadIdx.x] = vm[img*MM + threadIdx.x];
  // init C = A + diag(vM); rows/cols >= 100 -> 0
  #pragma unroll
  for (int a = 0; a < 7; ++a) {
    int r = ty + 16*a;
    #pragma unroll
    for (int b = 0; b < 7; ++b) {
      int j = tx + 16*b;
      float v2 = (r < 100 && j < 100) ? ad[(img*MM + r)*MM + j] : 0.0f;
      if (r == j && r < 100) v2 += vm[img*MM + r];
      C[a][b] = v2;
    }
  }
  for (int p = 0; p < 7; ++p) {
    int k0 = p*16;
    int nbp = (p == 6) ? 4 : 16;
    // ---- P1: stage panel-col strip S + panel rows Pr (phase-start values)
    #pragma unroll
    for (int a = 0; a < 7; ++a) {
      int r = ty + 16*a;
      float val = 0.0f;
      #pragma unroll
      for (int b = 0; b < 7; ++b) if (b == p) val = C[a][b];
      S[r*17 + tx] = (r < 100 && tx < nbp) ? val : 0.0f;
    }
    {
      float pv[7];
      #pragma unroll
      for (int b = 0; b < 7; ++b) pv[b] = 0.0f;
      #pragma unroll
      for (int a = 0; a < 7; ++a) {
        #pragma unroll
        for (int b = 0; b < 7; ++b) if (a == p) pv[b] = C[a][b];
      }
      #pragma unroll
      for (int b = 0; b < 7; ++b) Pr[ty*113 + tx + 16*b] = pv[b];
    }
    __syncthreads();                                   // B1
    // ---- P2: wave 0 register-resident strip factorization (no pivoting)
    if (threadIdx.x < 64) {
      int lane = threadIdx.x;
      float P0[16], P1[16];
      #pragma unroll
      for (int c = 0; c < 16; ++c) {
        P0[c] = S[lane*17 + c];
        P1[c] = (lane + 64 < 112) ? S[(lane + 64)*17 + c] : 0.0f;
      }
      #pragma unroll
      for (int kk = 0; kk < 16; ++kk) {
        if (kk < nbp) {
          int kg = k0 + kk;
          int r1 = lane + 64;
          bool khigh = kg >= 64; int kl = kg & 63;
          float pivinv = 1.0f / flt_readlane(khigh ? P1[kk] : P0[kk], kl);
          float pr[16];
          #pragma unroll
          for (int c = 0; c < 16; ++c) {
            float pv = flt_readlane(khigh ? P1[c] : P0[c], kl);
            pr[c] = (c == kk) ? pivinv : pv*pivinv;
          }
          {
            float f = P0[kk];
            if (lane == kg) {
              #pragma unroll
              for (int c = 0; c < 16; ++c) P0[c] = pr[c];
            } else {
              #pragma unroll
              for (int c = 0; c < 16; ++c) P0[c] = ((c == kk) ? 0.0f : P0[c]) - f*pr[c];
            }
          }
          {
            float f = P1[kk];
            if (r1 == kg) {
              #pragma unroll
              for (int c = 0; c < 16; ++c) P1[c] = pr[c];
            } else {
              #pragma unroll
              for (int c = 0; c < 16; ++c) P1[c] = ((c == kk) ? 0.0f : P1[c]) - f*pr[c];
            }
          }
        }
      }
      #pragma unroll
      for (int c = 0; c < 16; ++c) {
        S[lane*17 + c] = P0[c];
        if (lane + 64 < 112) S[(lane + 64)*17 + c] = P1[c];
      }
    }
    __syncthreads();                                   // B2
    // ---- P3: mask C in REGISTERS, trailing rank-16 update, panel-col writeback
    #pragma unroll
    for (int a = 0; a < 7; ++a) {
      int r = ty + 16*a;
      bool prow_ = (r >= k0) && (r < k0 + 16);
      #pragma unroll
      for (int b = 0; b < 7; ++b) {
        if (r >= 100 || b == p || prow_) C[a][b] = 0.0f;
      }
    }
    #pragma unroll 4
    for (int t = 0; t < 16; ++t) {
      bool tok = (t < nbp);
      float bt[7], sa[7];
      #pragma unroll
      for (int b = 0; b < 7; ++b) bt[b] = tok ? Pr[t*113 + tx + 16*b] : 0.0f;
      #pragma unroll
      for (int a = 0; a < 7; ++a) sa[a] = S[(ty + 16*a)*17 + t];
      #pragma unroll
      for (int a = 0; a < 7; ++a)
        #pragma unroll
        for (int b = 0; b < 7; ++b) C[a][b] += sa[a]*bt[b];
    }
    #pragma unroll
    for (int a = 0; a < 7; ++a) {
      int r = ty + 16*a;
      float sval = S[r*17 + tx];
      #pragma unroll
      for (int b = 0; b < 7; ++b) if (b == p) C[a][b] = sval;
    }
    __syncthreads();                                   // B3 (WAR on S/Pr)
  }
  // Bm = Dv^{-1} - X
  #pragma unroll
  for (int a = 0; a < 7; ++a) {
    int r = ty + 16*a; if (r >= 100) continue;
    float dinv = 1.0f / svm[r];
    #pragma unroll
    for (int b = 0; b < 7; ++b) {
      int c = tx + 16*b; if (c >= 100) continue;
      float val = ((c == r) ? dinv : 0.0f) - C[a][b];
      out[OUT_B + (img*MM + r)*MM + c] = val;
    }
  }
}

extern "C" void kernel_launch(void* const* d_in, const int* in_sizes, int n_in,
                              void* d_out, int out_size, void* d_ws, size_t ws_size,
                              hipStream_t stream) {
  const float* pts = (const float*)d_in[0];
  float* out = (float*)d_out;
  char* ws = (char*)d_ws;
  float* vd  = (float*)(ws + OFF_VD);
  float* vmd = (float*)(ws + OFF_VM);
  float* ad  = (float*)(ws + OFF_AD);

  hipLaunchKernelGGL(k_vpart, dim3(BB*16 + MU_VP/MU_PER), dim3(256), 0, stream, pts, vd, out);
  hipLaunchKernelGGL(k_Asel, dim3(BB*28 + MU_AS/MU_PER), dim3(256), 0, stream, pts, vd, out, ad, vmd);
  hipLaunchKernelGGL(k_inv_m, dim3(BB + MU_IV/MU_PER), dim3(256), 0, stream, ad, vmd, pts, out);
}

// Round 11
// 201.411 us; speedup vs baseline: 1.0516x; 1.0516x over previous
//
#include <hip/hip_runtime.h>
#include <math.h>

#ifndef M_PI
#define M_PI 3.14159265358979323846
#endif

#define BB 8
#define NN 512
#define KK 64
#define GG 4096
#define MM 100

// ---------------- workspace layout (byte offsets) ----------------
// vd: TWO fp64 partial halves (split-K); vm / ad fp32
#define SZ_VD    (BB*GG*8u*2u)
#define OFF_VD   0u
#define SZ_VM    (BB*MM*4u)
#define OFF_VM   (OFF_VD + SZ_VD)
#define SZ_AD    (BB*MM*MM*4u)
#define OFF_AD   (OFF_VM + SZ_VM)

// ---------------- output layout (float element offsets) ----------------
#define OUT_M  0
#define OUT_V  (BB*NN*GG)               // 16,777,216
#define OUT_A  (OUT_V + BB*GG)          // 16,809,984
#define OUT_B  (OUT_A + BB*MM*MM)      // 16,889,984
#define OUT_MI (OUT_B + BB*MM*MM)      // 16,969,984

// ---------------- m-unit allocation across dispatches ----------------
#define MU_PER 8
#define MU_VP 4096            // with k_vpart   (units 0..4095)       -> 512 blocks
#define MU_AS 2048            // with k_Asel    (units 4096..6143)    -> 256 blocks
#define MU_IV 10240           // with k_inv_m   (units 6144..16383)   -> 1280 blocks

__device__ __forceinline__ void m_units(const float* __restrict__ pts,
                                        float* __restrict__ out, int u0, int cnt) {
  const float CM = (float)(1.0/(2.0*M_PI*128.0));
  for (int k = 0; k < cnt; ++k) {
    int u = u0 + k;
    int t = u*256 + (int)threadIdx.x;
    int e = t << 2;
    int img = e >> 21;
    int rem = e & ((1 << 21) - 1);
    int n = rem >> 12;
    int g = rem & 4095;
    int iy = g >> 6, ix = g & 63;       // e%4==0 -> ix%4==0
    float x = pts[(img*NN + n)*2 + 0];
    float y = pts[(img*NN + n)*2 + 1];
    float dy = y - (8.0f*iy + 4.0f);
    float ey = __expf(dy*dy*(-0.5f/128.0f));
    float4 r;
    float dx0 = x - (8.0f*ix + 4.0f);
    float dx1 = x - (8.0f*(ix+1) + 4.0f);
    float dx2 = x - (8.0f*(ix+2) + 4.0f);
    float dx3 = x - (8.0f*(ix+3) + 4.0f);
    r.x = ey*__expf(dx0*dx0*(-0.5f/128.0f))*CM;
    r.y = ey*__expf(dx1*dx1*(-0.5f/128.0f))*CM;
    r.z = ey*__expf(dx2*dx2*(-0.5f/128.0f))*CM;
    r.w = ey*__expf(dx3*dx3*(-0.5f/128.0f))*CM;
    *reinterpret_cast<float4*>(&out[OUT_M + e]) = r;
  }
}

__device__ __forceinline__ float flt_readlane(float v, int l) {
  return __int_as_float(__builtin_amdgcn_readlane(__float_as_int(v), l));
}

// ============ K2: v — SPLIT-K (2 blocks per tile) + recurrence exp tables ============
// r10 post-mortem: vpart had only 128 real blocks (0.5/CU) and 32k fp64 exps
// per block. (1) Split-K x2: each block sums 256 of 512 points, fp64 partial
// to vd[half]; Asel adds halves in fixed order (deterministic, ~1e-16 rel
// change). (2) exp recurrence along rows: E(r+1)=E(r)*R, R*=Q, Q=exp(-128a)
// -> 2 exps + 32 mults per thread/chunk instead of 16 exps (error ~1e-15;
// underflow edge <= ~1e-218 absolute, negligible). One wave owns one table:
// wave-uniform branches, conflict-free column writes.
__global__ __launch_bounds__(256) void k_vpart(const float* __restrict__ pts,
                                               double* __restrict__ vd,
                                               float* __restrict__ out) {
  __shared__ double sEy2[16][66], sEy3[16][66], sEx2[16][66], sEx3[16][66];
  __shared__ float px[256], py[256];
  int bid = blockIdx.x;                 // (img*16+tile)*2+half  |  m blocks
  if (bid >= BB*32) { m_units(pts, out, (bid - BB*32)*MU_PER, MU_PER); return; }
  int half = bid & 1;
  int rem = bid >> 1;
  int tile = rem & 15;
  int img = rem >> 4;
  int iy0 = (tile >> 2) << 4;
  int ix0 = (tile & 3) << 4;
  int tx = threadIdx.x & 15, ty = threadIdx.x >> 4;
  int n = threadIdx.x & 63;             // point-in-chunk this thread fills
  int tbl = threadIdx.x >> 6;           // wave -> table (wave-uniform)
  for (int s = threadIdx.x; s < 256; s += 256) {
    px[s] = pts[(img*NN + half*256 + s)*2 + 0];
    py[s] = pts[(img*NN + half*256 + s)*2 + 1];
  }
  const double alpha = (tbl & 1) ? (1.0/128.0) : (0.5/96.0);
  const double Q = exp(-128.0*alpha);   // exp(-2/3) or exp(-1), hoisted
  const int base = (tbl >= 2) ? ix0 : iy0;
  double* dst = (tbl == 0) ? &sEy2[0][0] : (tbl == 1) ? &sEy3[0][0]
              : (tbl == 2) ? &sEx2[0][0] : &sEx3[0][0];
  double aV = 0.0, aM = 0.0;
  for (int kc = 0; kc < 4; ++kc) {
    int nbl = kc << 6;
    __syncthreads();                    // WAR on LDS (and px/py ready on kc=0)
    {
      int nn = nbl + n;
      double coord = (tbl >= 2) ? (double)px[nn] : (double)py[nn];
      double d0 = coord - (8.0*base + 4.0);
      double E = exp(-alpha*d0*d0);     // row 0 value
      double R = exp(alpha*(16.0*d0 - 64.0));
      #pragma unroll
      for (int row = 0; row < 16; ++row) {
        dst[row*66 + n] = E;
        E *= R; R *= Q;
      }
    }
    __syncthreads();
    #pragma unroll 8
    for (int n2 = 0; n2 < 64; ++n2) {
      aV += sEy2[ty][n2]*sEx2[tx][n2];
      aM += sEy3[ty][n2]*sEx3[tx][n2];
    }
  }
  const double CTV = 1.0/((2.0*M_PI*96.0)*(2.0*M_PI*128.0));
  const double CM2 = 1.0/((2.0*M_PI*128.0)*(2.0*M_PI*128.0));
  vd[half*(BB*GG) + img*GG + (iy0 + ty)*KK + ix0 + tx] = CTV*aV - CM2*aM;
}

// ---------------- LDS union for fused select+A ----------------
union AselU {
  struct {
    unsigned int ku[GG];                       // 16 KB fp32 sortable keys
    unsigned int hist4[4][256];                // per-wave histogram copies
    unsigned int wq[4];                        // wave totals for suffix scan
    unsigned int sPref, sMask;
    unsigned int sRem, sPickB, sPickRem, sCGt, sCEq;
    int tie[128];
  } se;                                        // ~21 KB
  struct {
    float sxi[16][130], syi[16][130], sti[16][130];
    float sxj[16][130], syj[16][130], stj[16][130];
    float px[NN], py[NN];
    float cxi[16], cyi[16], cxj[16], cyj[16];
  } ka;                                        // 54,272 B (max)
};

// ---------------- bitonic sort of 128 ints ascending (shared array) ----------------
__device__ __forceinline__ void bitonic128(int* a, int tid) {
  for (int kk = 2; kk <= 128; kk <<= 1)
    for (int jj = kk >> 1; jj > 0; jj >>= 1) {
      if (tid < 128) {
        int p = tid ^ jj;
        if (p > tid) {
          int x = a[tid], y = a[p];
          bool up = ((tid & kk) == 0);
          if (up ? (x > y) : (x < y)) { a[tid] = y; a[p] = x; }
        }
      }
      __syncthreads();
    }
}

// ============ K34: FUSED fp32 top-100 radix select + A assembly + m blocks ============
__global__ __launch_bounds__(256) void k_Asel(const float* __restrict__ pts,
                                              const double* __restrict__ vd,
                                              float* __restrict__ out,
                                              float* __restrict__ ad,
                                              float* __restrict__ vm) {
  __shared__ AselU u;
  __shared__ int selFinal[128];         // survives the union switch se -> ka
  int bid = blockIdx.x;                 // img*28 + tri-tile  |  m blocks
  if (bid >= BB*28) { m_units(pts, out, MU_VP + (bid - BB*28)*MU_PER, MU_PER); return; }
  int img = bid / 28;
  int tile = bid - img*28;
  bool tile0 = (tile == 0);
  int tid = threadIdx.x;
  int wv = tid >> 6;
  int lane = tid & 63;

  // ================= select phase (LDS as u.se) =================
  for (int t = 0; t < 16; ++t) {
    int g = t*256 + tid;
    // deterministic fixed-order sum of the two split-K partials
    float v = (float)(vd[img*GG + g] + vd[BB*GG + img*GG + g]);
    if (tile0) out[OUT_V + img*GG + g] = fmaxf(v, 1e-6f);
    int w = __float_as_int(v);
    u.se.ku[g] = (w < 0) ? ~(unsigned)w : ((unsigned)w | 0x80000000u);
  }
  if (tid == 0) {
    u.se.sRem = 100; u.se.sPref = 0u; u.se.sMask = 0u;
    u.se.sCGt = 0; u.se.sCEq = 0;
  }
  // ---- 4 radix passes, MSB first ----
  for (int shift = 24; shift >= 0; shift -= 8) {
    for (int c = 0; c < 4; ++c) u.se.hist4[c][tid] = 0;
    __syncthreads();                    // ku/state ready, hist zeroed
    unsigned mask = u.se.sMask, pref = u.se.sPref;
    for (int t = 0; t < 16; ++t) {
      unsigned k = u.se.ku[t*256 + tid];
      if ((k & mask) == pref)
        atomicAdd(&u.se.hist4[wv][(k >> shift) & 255u], 1u);
    }
    __syncthreads();
    unsigned tot = u.se.hist4[0][tid] + u.se.hist4[1][tid]
                 + u.se.hist4[2][tid] + u.se.hist4[3][tid];
    // wave-level inclusive SUFFIX scan over the 64 bins this wave owns
    unsigned val = tot;
    #pragma unroll
    for (int off = 1; off < 64; off <<= 1) {
      unsigned o = (unsigned)__shfl_down((int)val, off);
      if (lane + off < 64) val += o;
    }
    if (lane == 0) u.se.wq[wv] = val;   // whole-wave total
    __syncthreads();
    unsigned suf = val;                 // + totals of higher waves (higher digits)
    for (int w2 = wv + 1; w2 < 4; ++w2) suf += u.se.wq[w2];
    unsigned rem = u.se.sRem;
    unsigned sgt = suf - tot;           // count with digit strictly greater
    if (suf >= rem && sgt < rem) { u.se.sPickB = (unsigned)tid; u.se.sPickRem = rem - sgt; }
    __syncthreads();
    if (tid == 0) {
      u.se.sPref |= u.se.sPickB << shift;
      u.se.sMask |= 255u << shift;
      u.se.sRem   = u.se.sPickRem;
    }
    __syncthreads();
  }
  // ---- collect: all k > T, plus r smallest-index ties (k == T) ----
  unsigned T = u.se.sPref;              // exact 100th-largest fp32 key
  for (int t = 0; t < 16; ++t) {
    int g = t*256 + tid;
    unsigned k = u.se.ku[g];
    if (k > T) {
      unsigned p = atomicAdd(&u.se.sCGt, 1u);   // p <= 98 always
      selFinal[p] = g;
    } else if (k == T) {
      unsigned p = atomicAdd(&u.se.sCEq, 1u);
      if (p < 128) u.se.tie[p] = g;     // >128 exact-equal boundary: pathological
    }
  }
  __syncthreads();
  unsigned cgt = u.se.sCGt, ceq = u.se.sCEq, r = u.se.sRem;
  if (tid < 128 && tid >= (int)((ceq < 128u) ? ceq : 128u)) u.se.tie[tid] = 0x7fffffff;
  __syncthreads();
  bitonic128(u.se.tie, tid);                     // ties ascending by index
  if (tid < (int)r) selFinal[cgt + tid] = u.se.tie[tid];
  if (tid >= MM && tid < 128) selFinal[tid] = 0x7fffffff;
  __syncthreads();
  bitonic128(selFinal, tid);                     // final Minds ascending
  if (tile0 && tid < MM) {
    int mi = selFinal[tid];
    out[OUT_MI + img*MM + tid] = (float)mi;      // whole out buffer is float32
    float vsel = (float)(vd[img*GG + mi] + vd[BB*GG + img*GG + mi]);
    vm[img*MM + tid] = fmaxf(vsel, 1e-6f) + 1e-10f;  // ref fp32 semantics
  }
  __syncthreads();                               // done with u.se before ka overwrite

  // ================= A phase (LDS as u.ka) =================
  int it = 0, trem = tile;
  while (trem >= 7 - it) { trem -= 7 - it; ++it; }
  int jt = it + trem;
  int i0 = it*16, j0 = jt*16;
  int tj = tid & 15, ti = tid >> 4;
  int i = i0 + ti, j = j0 + tj;
  const float CM = (float)(1.0/(2.0*M_PI*128.0));
  const float C1 = (float)(1.0/(2.0*M_PI*128.0));   // g1 scale (2*pi*2*sigma2)
  const float C2 = (float)(1.0/(2.0*M_PI*96.0));    // h scale (2*pi*s2)
  for (int s = tid; s < NN; s += 256) {
    u.ka.px[s] = pts[(img*NN + s)*2 + 0];
    u.ka.py[s] = pts[(img*NN + s)*2 + 1];
  }
  if (tid < 16) {
    int gi = i0 + tid; if (gi > 99) gi = 99;
    int mi = selFinal[gi];
    u.ka.cxi[tid] = 8.0f*(mi & 63) + 4.0f;
    u.ka.cyi[tid] = 8.0f*(mi >> 6) + 4.0f;
  } else if (tid < 32) {
    int rr = tid - 16;
    int gj = j0 + rr; if (gj > 99) gj = 99;
    int mj = selFinal[gj];
    u.ka.cxj[rr] = 8.0f*(mj & 63) + 4.0f;
    u.ka.cyj[rr] = 8.0f*(mj >> 6) + 4.0f;
  }
  float aV = 0.0f, aM = 0.0f;
  for (int nc = 0; nc < NN; nc += 128) {
    __syncthreads();
    for (int s = tid; s < 16*128; s += 256) {
      int row = s >> 7, n = s & 127;
      float x = u.ka.px[nc + n], y = u.ka.py[nc + n];
      float fxi = x - u.ka.cxi[row], fyi = y - u.ka.cyi[row];
      u.ka.sxi[row][n] = fxi; u.ka.syi[row][n] = fyi;
      u.ka.sti[row][n] = __expf((fxi*fxi + fyi*fyi)*(-0.5f/128.0f))*CM;
      float fxj = x - u.ka.cxj[row], fyj = y - u.ka.cyj[row];
      u.ka.sxj[row][n] = fxj; u.ka.syj[row][n] = fyj;
      u.ka.stj[row][n] = __expf((fxj*fxj + fyj*fyj)*(-0.5f/128.0f))*CM;
    }
    __syncthreads();
    #pragma unroll 4
    for (int n = 0; n < 128; ++n) {
      float xi = u.ka.sxi[ti][n], yi = u.ka.syi[ti][n], tii = u.ka.sti[ti][n];
      float xj = u.ka.sxj[tj][n], yj = u.ka.syj[tj][n], tjj = u.ka.stj[tj][n];
      float ddx = xj - xi, ddy = yj - yi;
      float df = ddx*ddx + ddy*ddy;
      float sx = 0.5f*(xi + xj), sy = 0.5f*(yi + yj);
      float af = sx*sx + sy*sy;
      float g1 = __expf(df*(-0.5f/128.0f))*C1;
      float h  = __expf(af*(-0.5f/96.0f))*C2;
      aV += g1 + g1*h;
      aM += tii*tjj;
    }
  }
  if (i < 100 && j < 100) {
    float val = (i == j) ? 1e-10f : (float)((double)aV - (double)aM);
    out[OUT_A + (img*MM + i)*MM + j] = val;
    ad[(img*MM + i)*MM + j] = val;
    if (it != jt) {                     // mirror (diag tiles cover both in-tile)
      out[OUT_A + (img*MM + j)*MM + i] = val;
      ad[(img*MM + j)*MM + i] = val;
    }
  }
}

// ============ K5: FP32 GJ inversion (blocks 0..7) + remaining m blocks ============
__global__ __launch_bounds__(256)
void k_inv_m(const float* __restrict__ ad,
             const float* __restrict__ vm,
             const float* __restrict__ pts,
             float* __restrict__ out) {
  __shared__ float S[128*17];           //  8,704 B
  __shared__ float Pr[16*113];          //  7,232 B
  __shared__ float svm[112];            //    448 B  -> total 16,384 B
  if (blockIdx.x >= BB) {
    m_units(pts, out, MU_VP + MU_AS + ((int)blockIdx.x - BB)*MU_PER, MU_PER);
    return;
  }
  // ---- inversion part: no-pivot blocked fp32 GJ (SPD), Bm = Dv^{-1} - (A+Dv)^{-1}
  int img = blockIdx.x;
  int tx = threadIdx.x & 15, ty = threadIdx.x >> 4;   // ty in [0,16)
  float C[7][7];
  if (threadIdx.x < 100) svm[threadIdx.x] = vm[img*MM + threadIdx.x];
  // init C = A + diag(vM); rows/cols >= 100 -> 0
  #pragma unroll
  for (int a = 0; a < 7; ++a) {
    int r = ty + 16*a;
    #pragma unroll
    for (int b = 0; b < 7; ++b) {
      int j = tx + 16*b;
      float v2 = (r < 100 && j < 100) ? ad[(img*MM + r)*MM + j] : 0.0f;
      if (r == j && r < 100) v2 += vm[img*MM + r];
      C[a][b] = v2;
    }
  }
  for (int p = 0; p < 7; ++p) {
    int k0 = p*16;
    int nbp = (p == 6) ? 4 : 16;
    // ---- P1: stage panel-col strip S + panel rows Pr (phase-start values)
    #pragma unroll
    for (int a = 0; a < 7; ++a) {
      int r = ty + 16*a;
      float val = 0.0f;
      #pragma unroll
      for (int b = 0; b < 7; ++b) if (b == p) val = C[a][b];
      S[r*17 + tx] = (r < 100 && tx < nbp) ? val : 0.0f;
    }
    {
      float pv[7];
      #pragma unroll
      for (int b = 0; b < 7; ++b) pv[b] = 0.0f;
      #pragma unroll
      for (int a = 0; a < 7; ++a) {
        #pragma unroll
        for (int b = 0; b < 7; ++b) if (a == p) pv[b] = C[a][b];
      }
      #pragma unroll
      for (int b = 0; b < 7; ++b) Pr[ty*113 + tx + 16*b] = pv[b];
    }
    __syncthreads();                                   // B1
    // ---- P2: wave 0 register-resident strip factorization (no pivoting)
    if (threadIdx.x < 64) {
      int lane = threadIdx.x;
      float P0[16], P1[16];
      #pragma unroll
      for (int c = 0; c < 16; ++c) {
        P0[c] = S[lane*17 + c];
        P1[c] = (lane + 64 < 112) ? S[(lane + 64)*17 + c] : 0.0f;
      }
      #pragma unroll
      for (int kk = 0; kk < 16; ++kk) {
        if (kk < nbp) {
          int kg = k0 + kk;
          int r1 = lane + 64;
          bool khigh = kg >= 64; int kl = kg & 63;
          float pivinv = 1.0f / flt_readlane(khigh ? P1[kk] : P0[kk], kl);
          float pr[16];
          #pragma unroll
          for (int c = 0; c < 16; ++c) {
            float pv = flt_readlane(khigh ? P1[c] : P0[c], kl);
            pr[c] = (c == kk) ? pivinv : pv*pivinv;
          }
          {
            float f = P0[kk];
            if (lane == kg) {
              #pragma unroll
              for (int c = 0; c < 16; ++c) P0[c] = pr[c];
            } else {
              #pragma unroll
              for (int c = 0; c < 16; ++c) P0[c] = ((c == kk) ? 0.0f : P0[c]) - f*pr[c];
            }
          }
          {
            float f = P1[kk];
            if (r1 == kg) {
              #pragma unroll
              for (int c = 0; c < 16; ++c) P1[c] = pr[c];
            } else {
              #pragma unroll
              for (int c = 0; c < 16; ++c) P1[c] = ((c == kk) ? 0.0f : P1[c]) - f*pr[c];
            }
          }
        }
      }
      #pragma unroll
      for (int c = 0; c < 16; ++c) {
        S[lane*17 + c] = P0[c];
        if (lane + 64 < 112) S[(lane + 64)*17 + c] = P1[c];
      }
    }
    __syncthreads();                                   // B2
    // ---- P3: mask C in REGISTERS, trailing rank-16 update, panel-col writeback
    #pragma unroll
    for (int a = 0; a < 7; ++a) {
      int r = ty + 16*a;
      bool prow_ = (r >= k0) && (r < k0 + 16);
      #pragma unroll
      for (int b = 0; b < 7; ++b) {
        if (r >= 100 || b == p || prow_) C[a][b] = 0.0f;
      }
    }
    #pragma unroll 4
    for (int t = 0; t < 16; ++t) {
      bool tok = (t < nbp);
      float bt[7], sa[7];
      #pragma unroll
      for (int b = 0; b < 7; ++b) bt[b] = tok ? Pr[t*113 + tx + 16*b] : 0.0f;
      #pragma unroll
      for (int a = 0; a < 7; ++a) sa[a] = S[(ty + 16*a)*17 + t];
      #pragma unroll
      for (int a = 0; a < 7; ++a)
        #pragma unroll
        for (int b = 0; b < 7; ++b) C[a][b] += sa[a]*bt[b];
    }
    #pragma unroll
    for (int a = 0; a < 7; ++a) {
      int r = ty + 16*a;
      float sval = S[r*17 + tx];
      #pragma unroll
      for (int b = 0; b < 7; ++b) if (b == p) C[a][b] = sval;
    }
    __syncthreads();                                   // B3 (WAR on S/Pr)
  }
  // Bm = Dv^{-1} - X
  #pragma unroll
  for (int a = 0; a < 7; ++a) {
    int r = ty + 16*a; if (r >= 100) continue;
    float dinv = 1.0f / svm[r];
    #pragma unroll
    for (int b = 0; b < 7; ++b) {
      int c = tx + 16*b; if (c >= 100) continue;
      float val = ((c == r) ? dinv : 0.0f) - C[a][b];
      out[OUT_B + (img*MM + r)*MM + c] = val;
    }
  }
}

extern "C" void kernel_launch(void* const* d_in, const int* in_sizes, int n_in,
                              void* d_out, int out_size, void* d_ws, size_t ws_size,
                              hipStream_t stream) {
  const float* pts = (const float*)d_in[0];
  float* out = (float*)d_out;
  char* ws = (char*)d_ws;
  double* vd  = (double*)(ws + OFF_VD);
  float* vmd = (float*)(ws + OFF_VM);
  float* ad  = (float*)(ws + OFF_AD);

  hipLaunchKernelGGL(k_vpart, dim3(BB*32 + MU_VP/MU_PER), dim3(256), 0, stream, pts, vd, out);
  hipLaunchKernelGGL(k_Asel, dim3(BB*28 + MU_AS/MU_PER), dim3(256), 0, stream, pts, vd, out, ad, vmd);
  hipLaunchKernelGGL(k_inv_m, dim3(BB + MU_IV/MU_PER), dim3(256), 0, stream, ad, vmd, pts, out);
}

// Round 12
// 195.783 us; speedup vs baseline: 1.0818x; 1.0287x over previous
//
#include <hip/hip_runtime.h>
#include <math.h>

#ifndef M_PI
#define M_PI 3.14159265358979323846
#endif

#define BB 8
#define NN 512
#define KK 64
#define GG 4096
#define MM 100

// ---------------- workspace layout (byte offsets) ----------------
// vd: TWO fp64 partial halves (split-K); vm / ad fp32
#define SZ_VD    (BB*GG*8u*2u)
#define OFF_VD   0u
#define SZ_VM    (BB*MM*4u)
#define OFF_VM   (OFF_VD + SZ_VD)
#define SZ_AD    (BB*MM*MM*4u)
#define OFF_AD   (OFF_VM + SZ_VM)

// ---------------- output layout (float element offsets) ----------------
#define OUT_M  0
#define OUT_V  (BB*NN*GG)               // 16,777,216
#define OUT_A  (OUT_V + BB*GG)          // 16,809,984
#define OUT_B  (OUT_A + BB*MM*MM)      // 16,889,984
#define OUT_MI (OUT_B + BB*MM*MM)      // 16,969,984

// ---------------- m-unit allocation across dispatches ----------------
#define MU_PER 8
#define MU_VP 4096            // with k_vpart   (units 0..4095)       -> 512 blocks
#define MU_AS 2048            // with k_Asel    (units 4096..6143)    -> 256 blocks
#define MU_IV 10240           // with k_inv_m   (units 6144..16383)   -> 1280 blocks

__device__ __forceinline__ void m_units(const float* __restrict__ pts,
                                        float* __restrict__ out, int u0, int cnt) {
  const float CM = (float)(1.0/(2.0*M_PI*128.0));
  for (int k = 0; k < cnt; ++k) {
    int u = u0 + k;
    int t = u*256 + (int)threadIdx.x;
    int e = t << 2;
    int img = e >> 21;
    int rem = e & ((1 << 21) - 1);
    int n = rem >> 12;
    int g = rem & 4095;
    int iy = g >> 6, ix = g & 63;       // e%4==0 -> ix%4==0
    float x = pts[(img*NN + n)*2 + 0];
    float y = pts[(img*NN + n)*2 + 1];
    float dy = y - (8.0f*iy + 4.0f);
    float ey = __expf(dy*dy*(-0.5f/128.0f));
    float4 r;
    float dx0 = x - (8.0f*ix + 4.0f);
    float dx1 = x - (8.0f*(ix+1) + 4.0f);
    float dx2 = x - (8.0f*(ix+2) + 4.0f);
    float dx3 = x - (8.0f*(ix+3) + 4.0f);
    r.x = ey*__expf(dx0*dx0*(-0.5f/128.0f))*CM;
    r.y = ey*__expf(dx1*dx1*(-0.5f/128.0f))*CM;
    r.z = ey*__expf(dx2*dx2*(-0.5f/128.0f))*CM;
    r.w = ey*__expf(dx3*dx3*(-0.5f/128.0f))*CM;
    *reinterpret_cast<float4*>(&out[OUT_M + e]) = r;
  }
}

// 512-thread variant: cnt units, 2 units per pass (512 thr x float4 = 2 units)
__device__ __forceinline__ void m_units512(const float* __restrict__ pts,
                                           float* __restrict__ out, int u0, int cnt) {
  const float CM = (float)(1.0/(2.0*M_PI*128.0));
  for (int k = 0; k < cnt/2; ++k) {
    int t = u0*256 + k*512 + (int)threadIdx.x;
    int e = t << 2;
    int img = e >> 21;
    int rem = e & ((1 << 21) - 1);
    int n = rem >> 12;
    int g = rem & 4095;
    int iy = g >> 6, ix = g & 63;
    float x = pts[(img*NN + n)*2 + 0];
    float y = pts[(img*NN + n)*2 + 1];
    float dy = y - (8.0f*iy + 4.0f);
    float ey = __expf(dy*dy*(-0.5f/128.0f));
    float4 r;
    float dx0 = x - (8.0f*ix + 4.0f);
    float dx1 = x - (8.0f*(ix+1) + 4.0f);
    float dx2 = x - (8.0f*(ix+2) + 4.0f);
    float dx3 = x - (8.0f*(ix+3) + 4.0f);
    r.x = ey*__expf(dx0*dx0*(-0.5f/128.0f))*CM;
    r.y = ey*__expf(dx1*dx1*(-0.5f/128.0f))*CM;
    r.z = ey*__expf(dx2*dx2*(-0.5f/128.0f))*CM;
    r.w = ey*__expf(dx3*dx3*(-0.5f/128.0f))*CM;
    *reinterpret_cast<float4*>(&out[OUT_M + e]) = r;
  }
}

__device__ __forceinline__ float flt_readlane(float v, int l) {
  return __int_as_float(__builtin_amdgcn_readlane(__float_as_int(v), l));
}

// ============ K2: v — SPLIT-K (2 blocks per tile) + recurrence exp tables ============
__global__ __launch_bounds__(256) void k_vpart(const float* __restrict__ pts,
                                               double* __restrict__ vd,
                                               float* __restrict__ out) {
  __shared__ double sEy2[16][66], sEy3[16][66], sEx2[16][66], sEx3[16][66];
  __shared__ float px[256], py[256];
  int bid = blockIdx.x;                 // (img*16+tile)*2+half  |  m blocks
  if (bid >= BB*32) { m_units(pts, out, (bid - BB*32)*MU_PER, MU_PER); return; }
  int half = bid & 1;
  int rem = bid >> 1;
  int tile = rem & 15;
  int img = rem >> 4;
  int iy0 = (tile >> 2) << 4;
  int ix0 = (tile & 3) << 4;
  int tx = threadIdx.x & 15, ty = threadIdx.x >> 4;
  int n = threadIdx.x & 63;             // point-in-chunk this thread fills
  int tbl = threadIdx.x >> 6;           // wave -> table (wave-uniform)
  for (int s = threadIdx.x; s < 256; s += 256) {
    px[s] = pts[(img*NN + half*256 + s)*2 + 0];
    py[s] = pts[(img*NN + half*256 + s)*2 + 1];
  }
  const double alpha = (tbl & 1) ? (1.0/128.0) : (0.5/96.0);
  const double Q = exp(-128.0*alpha);   // exp(-2/3) or exp(-1), hoisted
  const int base = (tbl >= 2) ? ix0 : iy0;
  double* dst = (tbl == 0) ? &sEy2[0][0] : (tbl == 1) ? &sEy3[0][0]
              : (tbl == 2) ? &sEx2[0][0] : &sEx3[0][0];
  double aV = 0.0, aM = 0.0;
  for (int kc = 0; kc < 4; ++kc) {
    int nbl = kc << 6;
    __syncthreads();                    // WAR on LDS (and px/py ready on kc=0)
    {
      int nn = nbl + n;
      double coord = (tbl >= 2) ? (double)px[nn] : (double)py[nn];
      double d0 = coord - (8.0*base + 4.0);
      double E = exp(-alpha*d0*d0);     // row 0 value
      double R = exp(alpha*(16.0*d0 - 64.0));
      #pragma unroll
      for (int row = 0; row < 16; ++row) {
        dst[row*66 + n] = E;
        E *= R; R *= Q;
      }
    }
    __syncthreads();
    #pragma unroll 8
    for (int n2 = 0; n2 < 64; ++n2) {
      aV += sEy2[ty][n2]*sEx2[tx][n2];
      aM += sEy3[ty][n2]*sEx3[tx][n2];
    }
  }
  const double CTV = 1.0/((2.0*M_PI*96.0)*(2.0*M_PI*128.0));
  const double CM2 = 1.0/((2.0*M_PI*128.0)*(2.0*M_PI*128.0));
  vd[half*(BB*GG) + img*GG + (iy0 + ty)*KK + ix0 + tx] = CTV*aV - CM2*aM;
}

// ---------------- LDS union for fused select+A ----------------
union AselU {
  struct {
    unsigned int ku[GG];                       // 16 KB fp32 sortable keys
    unsigned int hist4[4][256];                // per-wave histogram copies
    unsigned int wq[4];                        // wave totals for suffix scan
    unsigned int sPref, sMask;
    unsigned int sRem, sPickB, sPickRem, sCGt, sCEq;
    int tie[128];
  } se;                                        // ~21 KB
  struct {
    float sxi[16][130], syi[16][130], sti[16][130];
    float sxj[16][130], syj[16][130], stj[16][130];
    float px[NN], py[NN];
    float cxi[16], cyi[16], cxj[16], cyj[16];
  } ka;                                        // 54,272 B (max)
};

// ---------------- bitonic sort of 128 ints ascending (shared array) ----------------
__device__ __forceinline__ void bitonic128(int* a, int tid) {
  for (int kk = 2; kk <= 128; kk <<= 1)
    for (int jj = kk >> 1; jj > 0; jj >>= 1) {
      if (tid < 128) {
        int p = tid ^ jj;
        if (p > tid) {
          int x = a[tid], y = a[p];
          bool up = ((tid & kk) == 0);
          if (up ? (x > y) : (x < y)) { a[tid] = y; a[p] = x; }
        }
      }
      __syncthreads();
    }
}

// ============ K34: FUSED fp32 top-100 radix select + A assembly + m blocks ============
__global__ __launch_bounds__(256) void k_Asel(const float* __restrict__ pts,
                                              const double* __restrict__ vd,
                                              float* __restrict__ out,
                                              float* __restrict__ ad,
                                              float* __restrict__ vm) {
  __shared__ AselU u;
  __shared__ int selFinal[128];         // survives the union switch se -> ka
  int bid = blockIdx.x;                 // img*28 + tri-tile  |  m blocks
  if (bid >= BB*28) { m_units(pts, out, MU_VP + (bid - BB*28)*MU_PER, MU_PER); return; }
  int img = bid / 28;
  int tile = bid - img*28;
  bool tile0 = (tile == 0);
  int tid = threadIdx.x;
  int wv = tid >> 6;
  int lane = tid & 63;

  // ================= select phase (LDS as u.se) =================
  for (int t = 0; t < 16; ++t) {
    int g = t*256 + tid;
    // deterministic fixed-order sum of the two split-K partials
    float v = (float)(vd[img*GG + g] + vd[BB*GG + img*GG + g]);
    if (tile0) out[OUT_V + img*GG + g] = fmaxf(v, 1e-6f);
    int w = __float_as_int(v);
    u.se.ku[g] = (w < 0) ? ~(unsigned)w : ((unsigned)w | 0x80000000u);
  }
  if (tid == 0) {
    u.se.sRem = 100; u.se.sPref = 0u; u.se.sMask = 0u;
    u.se.sCGt = 0; u.se.sCEq = 0;
  }
  // ---- 4 radix passes, MSB first ----
  for (int shift = 24; shift >= 0; shift -= 8) {
    for (int c = 0; c < 4; ++c) u.se.hist4[c][tid] = 0;
    __syncthreads();                    // ku/state ready, hist zeroed
    unsigned mask = u.se.sMask, pref = u.se.sPref;
    for (int t = 0; t < 16; ++t) {
      unsigned k = u.se.ku[t*256 + tid];
      if ((k & mask) == pref)
        atomicAdd(&u.se.hist4[wv][(k >> shift) & 255u], 1u);
    }
    __syncthreads();
    unsigned tot = u.se.hist4[0][tid] + u.se.hist4[1][tid]
                 + u.se.hist4[2][tid] + u.se.hist4[3][tid];
    // wave-level inclusive SUFFIX scan over the 64 bins this wave owns
    unsigned val = tot;
    #pragma unroll
    for (int off = 1; off < 64; off <<= 1) {
      unsigned o = (unsigned)__shfl_down((int)val, off);
      if (lane + off < 64) val += o;
    }
    if (lane == 0) u.se.wq[wv] = val;   // whole-wave total
    __syncthreads();
    unsigned suf = val;                 // + totals of higher waves (higher digits)
    for (int w2 = wv + 1; w2 < 4; ++w2) suf += u.se.wq[w2];
    unsigned rem = u.se.sRem;
    unsigned sgt = suf - tot;           // count with digit strictly greater
    if (suf >= rem && sgt < rem) { u.se.sPickB = (unsigned)tid; u.se.sPickRem = rem - sgt; }
    __syncthreads();
    if (tid == 0) {
      u.se.sPref |= u.se.sPickB << shift;
      u.se.sMask |= 255u << shift;
      u.se.sRem   = u.se.sPickRem;
    }
    __syncthreads();
  }
  // ---- collect: all k > T, plus r smallest-index ties (k == T) ----
  unsigned T = u.se.sPref;              // exact 100th-largest fp32 key
  for (int t = 0; t < 16; ++t) {
    int g = t*256 + tid;
    unsigned k = u.se.ku[g];
    if (k > T) {
      unsigned p = atomicAdd(&u.se.sCGt, 1u);   // p <= 98 always
      selFinal[p] = g;
    } else if (k == T) {
      unsigned p = atomicAdd(&u.se.sCEq, 1u);
      if (p < 128) u.se.tie[p] = g;     // >128 exact-equal boundary: pathological
    }
  }
  __syncthreads();
  unsigned cgt = u.se.sCGt, ceq = u.se.sCEq, r = u.se.sRem;
  if (tid < 128 && tid >= (int)((ceq < 128u) ? ceq : 128u)) u.se.tie[tid] = 0x7fffffff;
  __syncthreads();
  bitonic128(u.se.tie, tid);                     // ties ascending by index
  if (tid < (int)r) selFinal[cgt + tid] = u.se.tie[tid];
  if (tid >= MM && tid < 128) selFinal[tid] = 0x7fffffff;
  __syncthreads();
  bitonic128(selFinal, tid);                     // final Minds ascending
  if (tile0 && tid < MM) {
    int mi = selFinal[tid];
    out[OUT_MI + img*MM + tid] = (float)mi;      // whole out buffer is float32
    float vsel = (float)(vd[img*GG + mi] + vd[BB*GG + img*GG + mi]);
    vm[img*MM + tid] = fmaxf(vsel, 1e-6f) + 1e-10f;  // ref fp32 semantics
  }
  __syncthreads();                               // done with u.se before ka overwrite

  // ================= A phase (LDS as u.ka) =================
  int it = 0, trem = tile;
  while (trem >= 7 - it) { trem -= 7 - it; ++it; }
  int jt = it + trem;
  int i0 = it*16, j0 = jt*16;
  int tj = tid & 15, ti = tid >> 4;
  int i = i0 + ti, j = j0 + tj;
  const float CM = (float)(1.0/(2.0*M_PI*128.0));
  const float C1 = (float)(1.0/(2.0*M_PI*128.0));   // g1 scale (2*pi*2*sigma2)
  const float C2 = (float)(1.0/(2.0*M_PI*96.0));    // h scale (2*pi*s2)
  for (int s = tid; s < NN; s += 256) {
    u.ka.px[s] = pts[(img*NN + s)*2 + 0];
    u.ka.py[s] = pts[(img*NN + s)*2 + 1];
  }
  if (tid < 16) {
    int gi = i0 + tid; if (gi > 99) gi = 99;
    int mi = selFinal[gi];
    u.ka.cxi[tid] = 8.0f*(mi & 63) + 4.0f;
    u.ka.cyi[tid] = 8.0f*(mi >> 6) + 4.0f;
  } else if (tid < 32) {
    int rr = tid - 16;
    int gj = j0 + rr; if (gj > 99) gj = 99;
    int mj = selFinal[gj];
    u.ka.cxj[rr] = 8.0f*(mj & 63) + 4.0f;
    u.ka.cyj[rr] = 8.0f*(mj >> 6) + 4.0f;
  }
  float aV = 0.0f, aM = 0.0f;
  for (int nc = 0; nc < NN; nc += 128) {
    __syncthreads();
    for (int s = tid; s < 16*128; s += 256) {
      int row = s >> 7, n = s & 127;
      float x = u.ka.px[nc + n], y = u.ka.py[nc + n];
      float fxi = x - u.ka.cxi[row], fyi = y - u.ka.cyi[row];
      u.ka.sxi[row][n] = fxi; u.ka.syi[row][n] = fyi;
      u.ka.sti[row][n] = __expf((fxi*fxi + fyi*fyi)*(-0.5f/128.0f))*CM;
      float fxj = x - u.ka.cxj[row], fyj = y - u.ka.cyj[row];
      u.ka.sxj[row][n] = fxj; u.ka.syj[row][n] = fyj;
      u.ka.stj[row][n] = __expf((fxj*fxj + fyj*fyj)*(-0.5f/128.0f))*CM;
    }
    __syncthreads();
    #pragma unroll 4
    for (int n = 0; n < 128; ++n) {
      float xi = u.ka.sxi[ti][n], yi = u.ka.syi[ti][n], tii = u.ka.sti[ti][n];
      float xj = u.ka.sxj[tj][n], yj = u.ka.syj[tj][n], tjj = u.ka.stj[tj][n];
      float ddx = xj - xi, ddy = yj - yi;
      float df = ddx*ddx + ddy*ddy;
      float sx = 0.5f*(xi + xj), sy = 0.5f*(yi + yj);
      float af = sx*sx + sy*sy;
      float g1 = __expf(df*(-0.5f/128.0f))*C1;
      float h  = __expf(af*(-0.5f/96.0f))*C2;
      aV += g1 + g1*h;
      aM += tii*tjj;
    }
  }
  if (i < 100 && j < 100) {
    float val = (i == j) ? 1e-10f : (float)((double)aV - (double)aM);
    out[OUT_A + (img*MM + i)*MM + j] = val;
    ad[(img*MM + i)*MM + j] = val;
    if (it != jt) {                     // mirror (diag tiles cover both in-tile)
      out[OUT_A + (img*MM + j)*MM + i] = val;
      ad[(img*MM + j)*MM + i] = val;
    }
  }
}

// ============ K5: FP32 GJ inversion, 512-THREAD blocks (8 waves) + m blocks ============
// r11 model: inv block had 4 waves, each thread owning 7x7 of C -> P3 = 784
// FMA + 224 scalar LDS reads/thread/phase with poor latency hiding. Now 512
// threads (ty=tid>>5 in [0,16), tx=tid&31, cols tx+32b, b<4): per-thread P3
// halves (28 FMA, 11 LDS reads per t-iter) and the CU runs 8 waves. P2 (serial
// pivot chain, wave 0) unchanged. Cols 112..127 stay zero by construction.
#define PRS 130
__global__ __launch_bounds__(512)
void k_inv_m(const float* __restrict__ ad,
             const float* __restrict__ vm,
             const float* __restrict__ pts,
             float* __restrict__ out) {
  __shared__ float S[128*17];           //  8,704 B
  __shared__ float Pr[16*PRS];          //  8,320 B
  __shared__ float svm[112];            //    448 B  -> total ~17.5 KB
  if (blockIdx.x >= BB) {
    m_units512(pts, out, MU_VP + MU_AS + ((int)blockIdx.x - BB)*MU_PER, MU_PER);
    return;
  }
  int img = blockIdx.x;
  int tx = threadIdx.x & 31, ty = threadIdx.x >> 5;   // ty in [0,16), tx in [0,32)
  float C[7][4];
  if (threadIdx.x < 100) svm[threadIdx.x] = vm[img*MM + threadIdx.x];
  // init C = A + diag(vM); rows/cols >= 100 -> 0
  #pragma unroll
  for (int a = 0; a < 7; ++a) {
    int r = ty + 16*a;
    #pragma unroll
    for (int b = 0; b < 4; ++b) {
      int col = tx + 32*b;
      float v2 = (r < 100 && col < 100) ? ad[(img*MM + r)*MM + col] : 0.0f;
      if (r == col && r < 100) v2 += vm[img*MM + r];
      C[a][b] = v2;
    }
  }
  for (int p = 0; p < 7; ++p) {
    int k0 = p*16;
    int nbp = (p == 6) ? 4 : 16;
    // ---- P1: stage panel-col strip S + panel rows Pr (phase-start values)
    // S: the 16 threads per row with (col>>4)==p hold the panel columns.
    {
      int bp = p >> 1;                   // chunk containing panel p
      bool mine = ((tx >> 4) == (p & 1));// my half of that chunk
      int cq = tx & 15;                  // panel-local column
      #pragma unroll
      for (int a = 0; a < 7; ++a) {
        int r = ty + 16*a;
        if (mine) {
          float val = 0.0f;
          #pragma unroll
          for (int b = 0; b < 4; ++b) if (b == bp) val = C[a][b];
          S[r*17 + cq] = (r < 100 && cq < nbp) ? val : 0.0f;
        }
      }
    }
    {
      // panel rows k0..k0+15 owned by a==p: thread (ty,tx) holds C[p][b]
      float pv[4];
      #pragma unroll
      for (int b = 0; b < 4; ++b) pv[b] = 0.0f;
      #pragma unroll
      for (int a = 0; a < 7; ++a) {
        #pragma unroll
        for (int b = 0; b < 4; ++b) if (a == p) pv[b] = C[a][b];
      }
      #pragma unroll
      for (int b = 0; b < 4; ++b) Pr[ty*PRS + tx + 32*b] = pv[b];
    }
    __syncthreads();                                   // B1
    // ---- P2: wave 0 register-resident strip factorization (no pivoting)
    if (threadIdx.x < 64) {
      int lane = threadIdx.x;
      float P0[16], P1[16];
      #pragma unroll
      for (int c = 0; c < 16; ++c) {
        P0[c] = S[lane*17 + c];
        P1[c] = (lane + 64 < 112) ? S[(lane + 64)*17 + c] : 0.0f;
      }
      #pragma unroll
      for (int kk = 0; kk < 16; ++kk) {
        if (kk < nbp) {
          int kg = k0 + kk;
          int r1 = lane + 64;
          bool khigh = kg >= 64; int kl = kg & 63;
          float pivinv = 1.0f / flt_readlane(khigh ? P1[kk] : P0[kk], kl);
          float pr[16];
          #pragma unroll
          for (int c = 0; c < 16; ++c) {
            float pv = flt_readlane(khigh ? P1[c] : P0[c], kl);
            pr[c] = (c == kk) ? pivinv : pv*pivinv;
          }
          {
            float f = P0[kk];
            if (lane == kg) {
              #pragma unroll
              for (int c = 0; c < 16; ++c) P0[c] = pr[c];
            } else {
              #pragma unroll
              for (int c = 0; c < 16; ++c) P0[c] = ((c == kk) ? 0.0f : P0[c]) - f*pr[c];
            }
          }
          {
            float f = P1[kk];
            if (r1 == kg) {
              #pragma unroll
              for (int c = 0; c < 16; ++c) P1[c] = pr[c];
            } else {
              #pragma unroll
              for (int c = 0; c < 16; ++c) P1[c] = ((c == kk) ? 0.0f : P1[c]) - f*pr[c];
            }
          }
        }
      }
      #pragma unroll
      for (int c = 0; c < 16; ++c) {
        S[lane*17 + c] = P0[c];
        if (lane + 64 < 112) S[(lane + 64)*17 + c] = P1[c];
      }
    }
    __syncthreads();                                   // B2
    // ---- P3: mask C in REGISTERS, trailing rank-16 update, panel-col writeback
    #pragma unroll
    for (int a = 0; a < 7; ++a) {
      int r = ty + 16*a;
      bool prow_ = (r >= k0) && (r < k0 + 16);
      #pragma unroll
      for (int b = 0; b < 4; ++b) {
        int col = tx + 32*b;
        if (r >= 100 || (col >> 4) == p || prow_) C[a][b] = 0.0f;
      }
    }
    #pragma unroll 4
    for (int t = 0; t < 16; ++t) {
      bool tok = (t < nbp);
      float bt[4], sa[7];
      #pragma unroll
      for (int b = 0; b < 4; ++b) bt[b] = tok ? Pr[t*PRS + tx + 32*b] : 0.0f;
      #pragma unroll
      for (int a = 0; a < 7; ++a) sa[a] = S[(ty + 16*a)*17 + t];
      #pragma unroll
      for (int a = 0; a < 7; ++a)
        #pragma unroll
        for (int b = 0; b < 4; ++b) C[a][b] += sa[a]*bt[b];
    }
    #pragma unroll
    for (int a = 0; a < 7; ++a) {
      int r = ty + 16*a;
      #pragma unroll
      for (int b = 0; b < 4; ++b) {
        int col = tx + 32*b;
        if ((col >> 4) == p) C[a][b] = S[r*17 + (col & 15)];
      }
    }
    __syncthreads();                                   // B3 (WAR on S/Pr)
  }
  // Bm = Dv^{-1} - X
  #pragma unroll
  for (int a = 0; a < 7; ++a) {
    int r = ty + 16*a; if (r >= 100) continue;
    float dinv = 1.0f / svm[r];
    #pragma unroll
    for (int b = 0; b < 4; ++b) {
      int col = tx + 32*b; if (col >= 100) continue;
      float val = ((col == r) ? dinv : 0.0f) - C[a][b];
      out[OUT_B + (img*MM + r)*MM + col] = val;
    }
  }
}

extern "C" void kernel_launch(void* const* d_in, const int* in_sizes, int n_in,
                              void* d_out, int out_size, void* d_ws, size_t ws_size,
                              hipStream_t stream) {
  const float* pts = (const float*)d_in[0];
  float* out = (float*)d_out;
  char* ws = (char*)d_ws;
  double* vd  = (double*)(ws + OFF_VD);
  float* vmd = (float*)(ws + OFF_VM);
  float* ad  = (float*)(ws + OFF_AD);

  hipLaunchKernelGGL(k_vpart, dim3(BB*32 + MU_VP/MU_PER), dim3(256), 0, stream, pts, vd, out);
  hipLaunchKernelGGL(k_Asel, dim3(BB*28 + MU_AS/MU_PER), dim3(256), 0, stream, pts, vd, out, ad, vmd);
  hipLaunchKernelGGL(k_inv_m, dim3(BB + MU_IV/MU_PER), dim3(512), 0, stream, ad, vmd, pts, out);
}

// Round 13
// 193.751 us; speedup vs baseline: 1.0931x; 1.0105x over previous
//
#include <hip/hip_runtime.h>
#include <math.h>

#ifndef M_PI
#define M_PI 3.14159265358979323846
#endif

#define BB 8
#define NN 512
#define KK 64
#define GG 4096
#define MM 100

// ---------------- workspace layout (byte offsets) ----------------
// vd: FOUR fp64 partial quarters (split-K x4); vm / ad fp32
#define SZ_VD    (BB*GG*8u*4u)
#define OFF_VD   0u
#define SZ_VM    (BB*MM*4u)
#define OFF_VM   (OFF_VD + SZ_VD)
#define SZ_AD    (BB*MM*MM*4u)
#define OFF_AD   (OFF_VM + SZ_VM)

// ---------------- output layout (float element offsets) ----------------
#define OUT_M  0
#define OUT_V  (BB*NN*GG)               // 16,777,216
#define OUT_A  (OUT_V + BB*GG)          // 16,809,984
#define OUT_B  (OUT_A + BB*MM*MM)      // 16,889,984
#define OUT_MI (OUT_B + BB*MM*MM)      // 16,969,984

// ---------------- m-unit allocation across dispatches ----------------
#define MU_PER 8
#define MU_VP 4096            // with k_vpart   (units 0..4095)       -> 512 blocks
#define MU_AS 2048            // with k_Asel    (units 4096..6143)    -> 256 blocks
#define MU_IV 10240           // with k_inv_m   (units 6144..16383)   -> 1280 blocks

__device__ __forceinline__ void m_units(const float* __restrict__ pts,
                                        float* __restrict__ out, int u0, int cnt) {
  const float CM = (float)(1.0/(2.0*M_PI*128.0));
  for (int k = 0; k < cnt; ++k) {
    int u = u0 + k;
    int t = u*256 + (int)threadIdx.x;
    int e = t << 2;
    int img = e >> 21;
    int rem = e & ((1 << 21) - 1);
    int n = rem >> 12;
    int g = rem & 4095;
    int iy = g >> 6, ix = g & 63;       // e%4==0 -> ix%4==0
    float x = pts[(img*NN + n)*2 + 0];
    float y = pts[(img*NN + n)*2 + 1];
    float dy = y - (8.0f*iy + 4.0f);
    float ey = __expf(dy*dy*(-0.5f/128.0f));
    float4 r;
    float dx0 = x - (8.0f*ix + 4.0f);
    float dx1 = x - (8.0f*(ix+1) + 4.0f);
    float dx2 = x - (8.0f*(ix+2) + 4.0f);
    float dx3 = x - (8.0f*(ix+3) + 4.0f);
    r.x = ey*__expf(dx0*dx0*(-0.5f/128.0f))*CM;
    r.y = ey*__expf(dx1*dx1*(-0.5f/128.0f))*CM;
    r.z = ey*__expf(dx2*dx2*(-0.5f/128.0f))*CM;
    r.w = ey*__expf(dx3*dx3*(-0.5f/128.0f))*CM;
    *reinterpret_cast<float4*>(&out[OUT_M + e]) = r;
  }
}

// 512-thread variant: cnt units, 2 units per pass (512 thr x float4 = 2 units)
__device__ __forceinline__ void m_units512(const float* __restrict__ pts,
                                           float* __restrict__ out, int u0, int cnt) {
  const float CM = (float)(1.0/(2.0*M_PI*128.0));
  for (int k = 0; k < cnt/2; ++k) {
    int t = u0*256 + k*512 + (int)threadIdx.x;
    int e = t << 2;
    int img = e >> 21;
    int rem = e & ((1 << 21) - 1);
    int n = rem >> 12;
    int g = rem & 4095;
    int iy = g >> 6, ix = g & 63;
    float x = pts[(img*NN + n)*2 + 0];
    float y = pts[(img*NN + n)*2 + 1];
    float dy = y - (8.0f*iy + 4.0f);
    float ey = __expf(dy*dy*(-0.5f/128.0f));
    float4 r;
    float dx0 = x - (8.0f*ix + 4.0f);
    float dx1 = x - (8.0f*(ix+1) + 4.0f);
    float dx2 = x - (8.0f*(ix+2) + 4.0f);
    float dx3 = x - (8.0f*(ix+3) + 4.0f);
    r.x = ey*__expf(dx0*dx0*(-0.5f/128.0f))*CM;
    r.y = ey*__expf(dx1*dx1*(-0.5f/128.0f))*CM;
    r.z = ey*__expf(dx2*dx2*(-0.5f/128.0f))*CM;
    r.w = ey*__expf(dx3*dx3*(-0.5f/128.0f))*CM;
    *reinterpret_cast<float4*>(&out[OUT_M + e]) = r;
  }
}

__device__ __forceinline__ float flt_readlane(float v, int l) {
  return __int_as_float(__builtin_amdgcn_readlane(__float_as_int(v), l));
}

// ============ K2: v — SPLIT-K x4 + recurrence exp tables + double2 LDS reads ============
// r12: vpart was the largest dispatch (~66 us reconstructed). (1) split-K 4:
// 512 real blocks, each sums 128 of 512 points -> per-block inner work halves
// vs r11. (2) inner dot loop was LDS-issue-bound (4 b64 reads + 2 FMA/iter):
// manual pairwise unroll with double2 (b128) reads halves LDS issue. Add order
// per accumulator preserved exactly (sequential, no reassociation).
__global__ __launch_bounds__(256) void k_vpart(const float* __restrict__ pts,
                                               double* __restrict__ vd,
                                               float* __restrict__ out) {
  __shared__ double sEy2[16][66], sEy3[16][66], sEx2[16][66], sEx3[16][66];
  __shared__ float px[128], py[128];
  int bid = blockIdx.x;                 // (img*16+tile)*4+quarter  |  m blocks
  if (bid >= BB*64) { m_units(pts, out, (bid - BB*64)*MU_PER, MU_PER); return; }
  int quarter = bid & 3;
  int rem = bid >> 2;
  int tile = rem & 15;
  int img = rem >> 4;
  int iy0 = (tile >> 2) << 4;
  int ix0 = (tile & 3) << 4;
  int tx = threadIdx.x & 15, ty = threadIdx.x >> 4;
  int n = threadIdx.x & 63;             // point-in-chunk this thread fills
  int tbl = threadIdx.x >> 6;           // wave -> table (wave-uniform)
  if (threadIdx.x < 128) {
    px[threadIdx.x] = pts[(img*NN + quarter*128 + threadIdx.x)*2 + 0];
    py[threadIdx.x] = pts[(img*NN + quarter*128 + threadIdx.x)*2 + 1];
  }
  const double alpha = (tbl & 1) ? (1.0/128.0) : (0.5/96.0);
  const double Q = exp(-128.0*alpha);   // exp(-2/3) or exp(-1), hoisted
  const int base = (tbl >= 2) ? ix0 : iy0;
  double* dst = (tbl == 0) ? &sEy2[0][0] : (tbl == 1) ? &sEy3[0][0]
              : (tbl == 2) ? &sEx2[0][0] : &sEx3[0][0];
  double aV = 0.0, aM = 0.0;
  for (int kc = 0; kc < 2; ++kc) {
    int nbl = kc << 6;
    __syncthreads();                    // WAR on LDS (and px/py ready on kc=0)
    {
      int nn = nbl + n;
      double coord = (tbl >= 2) ? (double)px[nn] : (double)py[nn];
      double d0 = coord - (8.0*base + 4.0);
      double E = exp(-alpha*d0*d0);     // row 0 value
      double R = exp(alpha*(16.0*d0 - 64.0));
      #pragma unroll
      for (int row = 0; row < 16; ++row) {
        dst[row*66 + n] = E;
        E *= R; R *= Q;
      }
    }
    __syncthreads();
    #pragma unroll 8
    for (int n2 = 0; n2 < 64; n2 += 2) {
      double2 y2 = *reinterpret_cast<const double2*>(&sEy2[ty][n2]);
      double2 x2 = *reinterpret_cast<const double2*>(&sEx2[tx][n2]);
      double2 y3 = *reinterpret_cast<const double2*>(&sEy3[ty][n2]);
      double2 x3 = *reinterpret_cast<const double2*>(&sEx3[tx][n2]);
      aV += y2.x*x2.x; aV += y2.y*x2.y;  // same sequential order as scalar loop
      aM += y3.x*x3.x; aM += y3.y*x3.y;
    }
  }
  const double CTV = 1.0/((2.0*M_PI*96.0)*(2.0*M_PI*128.0));
  const double CM2 = 1.0/((2.0*M_PI*128.0)*(2.0*M_PI*128.0));
  vd[quarter*(BB*GG) + img*GG + (iy0 + ty)*KK + ix0 + tx] = CTV*aV - CM2*aM;
}

// ---------------- LDS union for fused select+A ----------------
union AselU {
  struct {
    unsigned int ku[GG];                       // 16 KB fp32 sortable keys
    unsigned int hist[32][257];                // 32 copies, bank-spread (32.9 KB)
    unsigned int wq[4];                        // wave totals for suffix scan
    unsigned int sPref, sMask;
    unsigned int sRem, sPickB, sPickRem, sCGt, sCEq;
    int tie[128];
  } se;                                        // ~50 KB
  struct {
    float sxi[16][130], syi[16][130], sti[16][130];
    float sxj[16][130], syj[16][130], stj[16][130];
    float px[NN], py[NN];
    float cxi[16], cyi[16], cxj[16], cyj[16];
  } ka;                                        // 54,272 B (max)
};

// ---------------- single-wave bitonic sort of 128 ints (2 elems/lane) ----------------
// Replaces the 28-barrier LDS bitonic: lanes 0..63 of the calling wave hold
// a[2L], a[2L+1]; partner exchange via shfl_xor. Zero block barriers inside.
// Verified mapping: idx=2L+s; jj>=2 partner lane = L^(jj>>1), same slot;
// "upper" = (L & (jj>>1)); dir up = ((2L & kk)==0); keep = (up^upper)?min:max.
__device__ __forceinline__ void wave_sort128(int* a) {
  int L = (int)(threadIdx.x & 63);
  int e0 = a[2*L], e1 = a[2*L + 1];
  for (int kk = 2; kk <= 128; kk <<= 1) {
    for (int jj = kk >> 1; jj >= 2; jj >>= 1) {
      int pl = jj >> 1;
      int o0 = __shfl_xor(e0, pl);
      int o1 = __shfl_xor(e1, pl);
      bool upper = (L & pl) != 0;
      bool up = ((2*L) & kk) == 0;
      if (up != upper) { e0 = min(e0, o0); e1 = min(e1, o1); }
      else             { e0 = max(e0, o0); e1 = max(e1, o1); }
    }
    bool up = ((2*L) & kk) == 0;
    int lo = min(e0, e1), hi = max(e0, e1);
    e0 = up ? lo : hi; e1 = up ? hi : lo;
  }
  a[2*L] = e0; a[2*L + 1] = e1;
}

// ============ K34: FUSED fp32 top-100 radix select + A assembly + m blocks ============
// r12 counters: 649K LDS bank conflicts (exponent-clustered keys -> same-bin
// atomicAdd 64-way serialization) + 56 block barriers in two LDS bitonics.
// Fix: 32 histogram copies (8 lanes/copy, stride-257 bank-spread summation)
// and single-wave register bitonic (4 barriers instead of 56).
__global__ __launch_bounds__(256) void k_Asel(const float* __restrict__ pts,
                                              const double* __restrict__ vd,
                                              float* __restrict__ out,
                                              float* __restrict__ ad,
                                              float* __restrict__ vm) {
  __shared__ AselU u;
  __shared__ int selFinal[128];         // survives the union switch se -> ka
  int bid = blockIdx.x;                 // img*28 + tri-tile  |  m blocks
  if (bid >= BB*28) { m_units(pts, out, MU_VP + (bid - BB*28)*MU_PER, MU_PER); return; }
  int img = bid / 28;
  int tile = bid - img*28;
  bool tile0 = (tile == 0);
  int tid = threadIdx.x;
  int wv = tid >> 6;
  int lane = tid & 63;
  int hc = tid >> 3;                    // histogram copy (8 lanes per copy)

  // ================= select phase (LDS as u.se) =================
  for (int t = 0; t < 16; ++t) {
    int g = t*256 + tid;
    // deterministic fixed-order sum of the four split-K partials
    float v = (float)(((vd[img*GG + g] + vd[BB*GG + img*GG + g])
                     + vd[2*BB*GG + img*GG + g]) + vd[3*BB*GG + img*GG + g]);
    if (tile0) out[OUT_V + img*GG + g] = fmaxf(v, 1e-6f);
    int w = __float_as_int(v);
    u.se.ku[g] = (w < 0) ? ~(unsigned)w : ((unsigned)w | 0x80000000u);
  }
  if (tid == 0) {
    u.se.sRem = 100; u.se.sPref = 0u; u.se.sMask = 0u;
    u.se.sCGt = 0; u.se.sCEq = 0;
  }
  // ---- 4 radix passes, MSB first ----
  for (int shift = 24; shift >= 0; shift -= 8) {
    for (int s = tid; s < 32*257; s += 256) (&u.se.hist[0][0])[s] = 0;
    __syncthreads();                    // ku/state ready, hist zeroed
    unsigned mask = u.se.sMask, pref = u.se.sPref;
    for (int t = 0; t < 16; ++t) {
      unsigned k = u.se.ku[t*256 + tid];
      if ((k & mask) == pref)
        atomicAdd(&u.se.hist[hc][(k >> shift) & 255u], 1u);
    }
    __syncthreads();
    unsigned tot = 0;
    #pragma unroll
    for (int c = 0; c < 32; ++c) tot += u.se.hist[c][tid];  // banks (c+tid)%32: conflict-free
    // wave-level inclusive SUFFIX scan over the 64 bins this wave owns
    unsigned val = tot;
    #pragma unroll
    for (int off = 1; off < 64; off <<= 1) {
      unsigned o = (unsigned)__shfl_down((int)val, off);
      if (lane + off < 64) val += o;
    }
    if (lane == 0) u.se.wq[wv] = val;   // whole-wave total
    __syncthreads();
    unsigned suf = val;                 // + totals of higher waves (higher digits)
    for (int w2 = wv + 1; w2 < 4; ++w2) suf += u.se.wq[w2];
    unsigned rem = u.se.sRem;
    unsigned sgt = suf - tot;           // count with digit strictly greater
    if (suf >= rem && sgt < rem) { u.se.sPickB = (unsigned)tid; u.se.sPickRem = rem - sgt; }
    __syncthreads();
    if (tid == 0) {
      u.se.sPref |= u.se.sPickB << shift;
      u.se.sMask |= 255u << shift;
      u.se.sRem   = u.se.sPickRem;
    }
    __syncthreads();
  }
  // ---- collect: all k > T, plus r smallest-index ties (k == T) ----
  unsigned T = u.se.sPref;              // exact 100th-largest fp32 key
  for (int t = 0; t < 16; ++t) {
    int g = t*256 + tid;
    unsigned k = u.se.ku[g];
    if (k > T) {
      unsigned p = atomicAdd(&u.se.sCGt, 1u);   // p <= 98 always
      selFinal[p] = g;
    } else if (k == T) {
      unsigned p = atomicAdd(&u.se.sCEq, 1u);
      if (p < 128) u.se.tie[p] = g;     // >128 exact-equal boundary: pathological
    }
  }
  __syncthreads();
  unsigned cgt = u.se.sCGt, ceq = u.se.sCEq, r = u.se.sRem;
  if (tid < 128 && tid >= (int)((ceq < 128u) ? ceq : 128u)) u.se.tie[tid] = 0x7fffffff;
  __syncthreads();
  if (tid < 64) wave_sort128(u.se.tie);          // ties ascending by index
  __syncthreads();
  if (tid < (int)r) selFinal[cgt + tid] = u.se.tie[tid];
  if (tid >= MM && tid < 128) selFinal[tid] = 0x7fffffff;
  __syncthreads();
  if (tid < 64) wave_sort128(selFinal);          // final Minds ascending
  __syncthreads();
  if (tile0 && tid < MM) {
    int mi = selFinal[tid];
    out[OUT_MI + img*MM + tid] = (float)mi;      // whole out buffer is float32
    float vsel = (float)(((vd[img*GG + mi] + vd[BB*GG + img*GG + mi])
                        + vd[2*BB*GG + img*GG + mi]) + vd[3*BB*GG + img*GG + mi]);
    vm[img*MM + tid] = fmaxf(vsel, 1e-6f) + 1e-10f;  // ref fp32 semantics
  }
  __syncthreads();                               // done with u.se before ka overwrite

  // ================= A phase (LDS as u.ka) =================
  int it = 0, trem = tile;
  while (trem >= 7 - it) { trem -= 7 - it; ++it; }
  int jt = it + trem;
  int i0 = it*16, j0 = jt*16;
  int tj = tid & 15, ti = tid >> 4;
  int i = i0 + ti, j = j0 + tj;
  const float CM = (float)(1.0/(2.0*M_PI*128.0));
  const float C1 = (float)(1.0/(2.0*M_PI*128.0));   // g1 scale (2*pi*2*sigma2)
  const float C2 = (float)(1.0/(2.0*M_PI*96.0));    // h scale (2*pi*s2)
  for (int s = tid; s < NN; s += 256) {
    u.ka.px[s] = pts[(img*NN + s)*2 + 0];
    u.ka.py[s] = pts[(img*NN + s)*2 + 1];
  }
  if (tid < 16) {
    int gi = i0 + tid; if (gi > 99) gi = 99;
    int mi = selFinal[gi];
    u.ka.cxi[tid] = 8.0f*(mi & 63) + 4.0f;
    u.ka.cyi[tid] = 8.0f*(mi >> 6) + 4.0f;
  } else if (tid < 32) {
    int rr = tid - 16;
    int gj = j0 + rr; if (gj > 99) gj = 99;
    int mj = selFinal[gj];
    u.ka.cxj[rr] = 8.0f*(mj & 63) + 4.0f;
    u.ka.cyj[rr] = 8.0f*(mj >> 6) + 4.0f;
  }
  float aV = 0.0f, aM = 0.0f;
  for (int nc = 0; nc < NN; nc += 128) {
    __syncthreads();
    for (int s = tid; s < 16*128; s += 256) {
      int row = s >> 7, n = s & 127;
      float x = u.ka.px[nc + n], y = u.ka.py[nc + n];
      float fxi = x - u.ka.cxi[row], fyi = y - u.ka.cyi[row];
      u.ka.sxi[row][n] = fxi; u.ka.syi[row][n] = fyi;
      u.ka.sti[row][n] = __expf((fxi*fxi + fyi*fyi)*(-0.5f/128.0f))*CM;
      float fxj = x - u.ka.cxj[row], fyj = y - u.ka.cyj[row];
      u.ka.sxj[row][n] = fxj; u.ka.syj[row][n] = fyj;
      u.ka.stj[row][n] = __expf((fxj*fxj + fyj*fyj)*(-0.5f/128.0f))*CM;
    }
    __syncthreads();
    #pragma unroll 4
    for (int n = 0; n < 128; ++n) {
      float xi = u.ka.sxi[ti][n], yi = u.ka.syi[ti][n], tii = u.ka.sti[ti][n];
      float xj = u.ka.sxj[tj][n], yj = u.ka.syj[tj][n], tjj = u.ka.stj[tj][n];
      float ddx = xj - xi, ddy = yj - yi;
      float df = ddx*ddx + ddy*ddy;
      float sx = 0.5f*(xi + xj), sy = 0.5f*(yi + yj);
      float af = sx*sx + sy*sy;
      float g1 = __expf(df*(-0.5f/128.0f))*C1;
      float h  = __expf(af*(-0.5f/96.0f))*C2;
      aV += g1 + g1*h;
      aM += tii*tjj;
    }
  }
  if (i < 100 && j < 100) {
    float val = (i == j) ? 1e-10f : (float)((double)aV - (double)aM);
    out[OUT_A + (img*MM + i)*MM + j] = val;
    ad[(img*MM + i)*MM + j] = val;
    if (it != jt) {                     // mirror (diag tiles cover both in-tile)
      out[OUT_A + (img*MM + j)*MM + i] = val;
      ad[(img*MM + j)*MM + i] = val;
    }
  }
}

// ============ K5: FP32 GJ inversion, 512-THREAD blocks (8 waves) + m blocks ============
#define PRS 130
__global__ __launch_bounds__(512)
void k_inv_m(const float* __restrict__ ad,
             const float* __restrict__ vm,
             const float* __restrict__ pts,
             float* __restrict__ out) {
  __shared__ float S[128*17];           //  8,704 B
  __shared__ float Pr[16*PRS];          //  8,320 B
  __shared__ float svm[112];            //    448 B  -> total ~17.5 KB
  if (blockIdx.x >= BB) {
    m_units512(pts, out, MU_VP + MU_AS + ((int)blockIdx.x - BB)*MU_PER, MU_PER);
    return;
  }
  int img = blockIdx.x;
  int tx = threadIdx.x & 31, ty = threadIdx.x >> 5;   // ty in [0,16), tx in [0,32)
  float C[7][4];
  if (threadIdx.x < 100) svm[threadIdx.x] = vm[img*MM + threadIdx.x];
  // init C = A + diag(vM); rows/cols >= 100 -> 0
  #pragma unroll
  for (int a = 0; a < 7; ++a) {
    int r = ty + 16*a;
    #pragma unroll
    for (int b = 0; b < 4; ++b) {
      int col = tx + 32*b;
      float v2 = (r < 100 && col < 100) ? ad[(img*MM + r)*MM + col] : 0.0f;
      if (r == col && r < 100) v2 += vm[img*MM + r];
      C[a][b] = v2;
    }
  }
  for (int p = 0; p < 7; ++p) {
    int k0 = p*16;
    int nbp = (p == 6) ? 4 : 16;
    // ---- P1: stage panel-col strip S + panel rows Pr (phase-start values)
    {
      int bp = p >> 1;                   // chunk containing panel p
      bool mine = ((tx >> 4) == (p & 1));// my half of that chunk
      int cq = tx & 15;                  // panel-local column
      #pragma unroll
      for (int a = 0; a < 7; ++a) {
        int r = ty + 16*a;
        if (mine) {
          float val = 0.0f;
          #pragma unroll
          for (int b = 0; b < 4; ++b) if (b == bp) val = C[a][b];
          S[r*17 + cq] = (r < 100 && cq < nbp) ? val : 0.0f;
        }
      }
    }
    {
      // panel rows k0..k0+15 owned by a==p: thread (ty,tx) holds C[p][b]
      float pv[4];
      #pragma unroll
      for (int b = 0; b < 4; ++b) pv[b] = 0.0f;
      #pragma unroll
      for (int a = 0; a < 7; ++a) {
        #pragma unroll
        for (int b = 0; b < 4; ++b) if (a == p) pv[b] = C[a][b];
      }
      #pragma unroll
      for (int b = 0; b < 4; ++b) Pr[ty*PRS + tx + 32*b] = pv[b];
    }
    __syncthreads();                                   // B1
    // ---- P2: wave 0 register-resident strip factorization (no pivoting)
    if (threadIdx.x < 64) {
      int lane = threadIdx.x;
      float P0[16], P1[16];
      #pragma unroll
      for (int c = 0; c < 16; ++c) {
        P0[c] = S[lane*17 + c];
        P1[c] = (lane + 64 < 112) ? S[(lane + 64)*17 + c] : 0.0f;
      }
      #pragma unroll
      for (int kk = 0; kk < 16; ++kk) {
        if (kk < nbp) {
          int kg = k0 + kk;
          int r1 = lane + 64;
          bool khigh = kg >= 64; int kl = kg & 63;
          float pivinv = 1.0f / flt_readlane(khigh ? P1[kk] : P0[kk], kl);
          float pr[16];
          #pragma unroll
          for (int c = 0; c < 16; ++c) {
            float pv = flt_readlane(khigh ? P1[c] : P0[c], kl);
            pr[c] = (c == kk) ? pivinv : pv*pivinv;
          }
          {
            float f = P0[kk];
            if (lane == kg) {
              #pragma unroll
              for (int c = 0; c < 16; ++c) P0[c] = pr[c];
            } else {
              #pragma unroll
              for (int c = 0; c < 16; ++c) P0[c] = ((c == kk) ? 0.0f : P0[c]) - f*pr[c];
            }
          }
          {
            float f = P1[kk];
            if (r1 == kg) {
              #pragma unroll
              for (int c = 0; c < 16; ++c) P1[c] = pr[c];
            } else {
              #pragma unroll
              for (int c = 0; c < 16; ++c) P1[c] = ((c == kk) ? 0.0f : P1[c]) - f*pr[c];
            }
          }
        }
      }
      #pragma unroll
      for (int c = 0; c < 16; ++c) {
        S[lane*17 + c] = P0[c];
        if (lane + 64 < 112) S[(lane + 64)*17 + c] = P1[c];
      }
    }
    __syncthreads();                                   // B2
    // ---- P3: mask C in REGISTERS, trailing rank-16 update, panel-col writeback
    #pragma unroll
    for (int a = 0; a < 7; ++a) {
      int r = ty + 16*a;
      bool prow_ = (r >= k0) && (r < k0 + 16);
      #pragma unroll
      for (int b = 0; b < 4; ++b) {
        int col = tx + 32*b;
        if (r >= 100 || (col >> 4) == p || prow_) C[a][b] = 0.0f;
      }
    }
    #pragma unroll 4
    for (int t = 0; t < 16; ++t) {
      bool tok = (t < nbp);
      float bt[4], sa[7];
      #pragma unroll
      for (int b = 0; b < 4; ++b) bt[b] = tok ? Pr[t*PRS + tx + 32*b] : 0.0f;
      #pragma unroll
      for (int a = 0; a < 7; ++a) sa[a] = S[(ty + 16*a)*17 + t];
      #pragma unroll
      for (int a = 0; a < 7; ++a)
        #pragma unroll
        for (int b = 0; b < 4; ++b) C[a][b] += sa[a]*bt[b];
    }
    #pragma unroll
    for (int a = 0; a < 7; ++a) {
      int r = ty + 16*a;
      #pragma unroll
      for (int b = 0; b < 4; ++b) {
        int col = tx + 32*b;
        if ((col >> 4) == p) C[a][b] = S[r*17 + (col & 15)];
      }
    }
    __syncthreads();                                   // B3 (WAR on S/Pr)
  }
  // Bm = Dv^{-1} - X
  #pragma unroll
  for (int a = 0; a < 7; ++a) {
    int r = ty + 16*a; if (r >= 100) continue;
    float dinv = 1.0f / svm[r];
    #pragma unroll
    for (int b = 0; b < 4; ++b) {
      int col = tx + 32*b; if (col >= 100) continue;
      float val = ((col == r) ? dinv : 0.0f) - C[a][b];
      out[OUT_B + (img*MM + r)*MM + col] = val;
    }
  }
}

extern "C" void kernel_launch(void* const* d_in, const int* in_sizes, int n_in,
                              void* d_out, int out_size, void* d_ws, size_t ws_size,
                              hipStream_t stream) {
  const float* pts = (const float*)d_in[0];
  float* out = (float*)d_out;
  char* ws = (char*)d_ws;
  double* vd  = (double*)(ws + OFF_VD);
  float* vmd = (float*)(ws + OFF_VM);
  float* ad  = (float*)(ws + OFF_AD);

  hipLaunchKernelGGL(k_vpart, dim3(BB*64 + MU_VP/MU_PER), dim3(256), 0, stream, pts, vd, out);
  hipLaunchKernelGGL(k_Asel, dim3(BB*28 + MU_AS/MU_PER), dim3(256), 0, stream, pts, vd, out, ad, vmd);
  hipLaunchKernelGGL(k_inv_m, dim3(BB + MU_IV/MU_PER), dim3(512), 0, stream, ad, vmd, pts, out);
}

// Round 14
// 190.392 us; speedup vs baseline: 1.1124x; 1.0176x over previous
//
#include <hip/hip_runtime.h>
#include <math.h>

#ifndef M_PI
#define M_PI 3.14159265358979323846
#endif

#define BB 8
#define NN 512
#define KK 64
#define GG 4096
#define MM 100

// ---------------- workspace layout (byte offsets) ----------------
// vd: FOUR fp64 partial quarters (split-K x4); ad: TWO fp32 partial halves
#define SZ_VD    (BB*GG*8u*4u)
#define OFF_VD   0u
#define SZ_VM    (BB*MM*4u)
#define OFF_VM   (OFF_VD + SZ_VD)
#define SZ_AD    (BB*MM*MM*4u*2u)
#define OFF_AD   (OFF_VM + SZ_VM)

// ---------------- output layout (float element offsets) ----------------
#define OUT_M  0
#define OUT_V  (BB*NN*GG)               // 16,777,216
#define OUT_A  (OUT_V + BB*GG)          // 16,809,984
#define OUT_B  (OUT_A + BB*MM*MM)      // 16,889,984
#define OUT_MI (OUT_B + BB*MM*MM)      // 16,969,984

// ---------------- m-unit allocation across dispatches ----------------
#define MU_PER 8
#define MU_VP 4096            // with k_vpart   (units 0..4095)       -> 512 blocks
#define MU_AS 2048            // with k_Asel    (units 4096..6143)    -> 256 blocks
#define MU_IV 10240           // with k_inv_m   (units 6144..16383)   -> 1280 blocks

__device__ __forceinline__ void m_units(const float* __restrict__ pts,
                                        float* __restrict__ out, int u0, int cnt) {
  const float CM = (float)(1.0/(2.0*M_PI*128.0));
  for (int k = 0; k < cnt; ++k) {
    int u = u0 + k;
    int t = u*256 + (int)threadIdx.x;
    int e = t << 2;
    int img = e >> 21;
    int rem = e & ((1 << 21) - 1);
    int n = rem >> 12;
    int g = rem & 4095;
    int iy = g >> 6, ix = g & 63;       // e%4==0 -> ix%4==0
    float x = pts[(img*NN + n)*2 + 0];
    float y = pts[(img*NN + n)*2 + 1];
    float dy = y - (8.0f*iy + 4.0f);
    float ey = __expf(dy*dy*(-0.5f/128.0f));
    float4 r;
    float dx0 = x - (8.0f*ix + 4.0f);
    float dx1 = x - (8.0f*(ix+1) + 4.0f);
    float dx2 = x - (8.0f*(ix+2) + 4.0f);
    float dx3 = x - (8.0f*(ix+3) + 4.0f);
    r.x = ey*__expf(dx0*dx0*(-0.5f/128.0f))*CM;
    r.y = ey*__expf(dx1*dx1*(-0.5f/128.0f))*CM;
    r.z = ey*__expf(dx2*dx2*(-0.5f/128.0f))*CM;
    r.w = ey*__expf(dx3*dx3*(-0.5f/128.0f))*CM;
    *reinterpret_cast<float4*>(&out[OUT_M + e]) = r;
  }
}

// 512-thread variant: cnt units, 2 units per pass (512 thr x float4 = 2 units)
__device__ __forceinline__ void m_units512(const float* __restrict__ pts,
                                           float* __restrict__ out, int u0, int cnt) {
  const float CM = (float)(1.0/(2.0*M_PI*128.0));
  for (int k = 0; k < cnt/2; ++k) {
    int t = u0*256 + k*512 + (int)threadIdx.x;
    int e = t << 2;
    int img = e >> 21;
    int rem = e & ((1 << 21) - 1);
    int n = rem >> 12;
    int g = rem & 4095;
    int iy = g >> 6, ix = g & 63;
    float x = pts[(img*NN + n)*2 + 0];
    float y = pts[(img*NN + n)*2 + 1];
    float dy = y - (8.0f*iy + 4.0f);
    float ey = __expf(dy*dy*(-0.5f/128.0f));
    float4 r;
    float dx0 = x - (8.0f*ix + 4.0f);
    float dx1 = x - (8.0f*(ix+1) + 4.0f);
    float dx2 = x - (8.0f*(ix+2) + 4.0f);
    float dx3 = x - (8.0f*(ix+3) + 4.0f);
    r.x = ey*__expf(dx0*dx0*(-0.5f/128.0f))*CM;
    r.y = ey*__expf(dx1*dx1*(-0.5f/128.0f))*CM;
    r.z = ey*__expf(dx2*dx2*(-0.5f/128.0f))*CM;
    r.w = ey*__expf(dx3*dx3*(-0.5f/128.0f))*CM;
    *reinterpret_cast<float4*>(&out[OUT_M + e]) = r;
  }
}

__device__ __forceinline__ float flt_readlane(float v, int l) {
  return __int_as_float(__builtin_amdgcn_readlane(__float_as_int(v), l));
}

// ============ K2: v — SPLIT-K x4 + recurrence exp tables + double2 LDS reads ============
__global__ __launch_bounds__(256) void k_vpart(const float* __restrict__ pts,
                                               double* __restrict__ vd,
                                               float* __restrict__ out) {
  __shared__ double sEy2[16][66], sEy3[16][66], sEx2[16][66], sEx3[16][66];
  __shared__ float px[128], py[128];
  int bid = blockIdx.x;                 // (img*16+tile)*4+quarter  |  m blocks
  if (bid >= BB*64) { m_units(pts, out, (bid - BB*64)*MU_PER, MU_PER); return; }
  int quarter = bid & 3;
  int rem = bid >> 2;
  int tile = rem & 15;
  int img = rem >> 4;
  int iy0 = (tile >> 2) << 4;
  int ix0 = (tile & 3) << 4;
  int tx = threadIdx.x & 15, ty = threadIdx.x >> 4;
  int n = threadIdx.x & 63;             // point-in-chunk this thread fills
  int tbl = threadIdx.x >> 6;           // wave -> table (wave-uniform)
  if (threadIdx.x < 128) {
    px[threadIdx.x] = pts[(img*NN + quarter*128 + threadIdx.x)*2 + 0];
    py[threadIdx.x] = pts[(img*NN + quarter*128 + threadIdx.x)*2 + 1];
  }
  const double alpha = (tbl & 1) ? (1.0/128.0) : (0.5/96.0);
  const double Q = exp(-128.0*alpha);   // exp(-2/3) or exp(-1), hoisted
  const int base = (tbl >= 2) ? ix0 : iy0;
  double* dst = (tbl == 0) ? &sEy2[0][0] : (tbl == 1) ? &sEy3[0][0]
              : (tbl == 2) ? &sEx2[0][0] : &sEx3[0][0];
  double aV = 0.0, aM = 0.0;
  for (int kc = 0; kc < 2; ++kc) {
    int nbl = kc << 6;
    __syncthreads();                    // WAR on LDS (and px/py ready on kc=0)
    {
      int nn = nbl + n;
      double coord = (tbl >= 2) ? (double)px[nn] : (double)py[nn];
      double d0 = coord - (8.0*base + 4.0);
      double E = exp(-alpha*d0*d0);     // row 0 value
      double R = exp(alpha*(16.0*d0 - 64.0));
      #pragma unroll
      for (int row = 0; row < 16; ++row) {
        dst[row*66 + n] = E;
        E *= R; R *= Q;
      }
    }
    __syncthreads();
    #pragma unroll 8
    for (int n2 = 0; n2 < 64; n2 += 2) {
      double2 y2 = *reinterpret_cast<const double2*>(&sEy2[ty][n2]);
      double2 x2 = *reinterpret_cast<const double2*>(&sEx2[tx][n2]);
      double2 y3 = *reinterpret_cast<const double2*>(&sEy3[ty][n2]);
      double2 x3 = *reinterpret_cast<const double2*>(&sEx3[tx][n2]);
      aV += y2.x*x2.x; aV += y2.y*x2.y;  // same sequential order as scalar loop
      aM += y3.x*x3.x; aM += y3.y*x3.y;
    }
  }
  const double CTV = 1.0/((2.0*M_PI*96.0)*(2.0*M_PI*128.0));
  const double CM2 = 1.0/((2.0*M_PI*128.0)*(2.0*M_PI*128.0));
  vd[quarter*(BB*GG) + img*GG + (iy0 + ty)*KK + ix0 + tx] = CTV*aV - CM2*aM;
}

// ---------------- LDS union for fused select+A ----------------
union AselU {
  struct {
    unsigned int ku[GG];                       // 16 KB fp32 sortable keys
    unsigned int hist[32][257];                // 32 copies, bank-spread (32.9 KB)
    unsigned int wq[4];                        // wave totals for suffix scan
    unsigned int sPref, sMask;
    unsigned int sRem, sPickB, sPickRem, sCGt, sCEq;
    int tie[128];
  } se;                                        // ~50 KB
  struct {
    float sxi[16][130], syi[16][130], sti[16][130];
    float sxj[16][130], syj[16][130], stj[16][130];
    float px[NN], py[NN];
    float cxi[16], cyi[16], cxj[16], cyj[16];
  } ka;                                        // 54,272 B (max)
};

// ---------------- single-wave bitonic sort of 128 ints (2 elems/lane) ----------------
__device__ __forceinline__ void wave_sort128(int* a) {
  int L = (int)(threadIdx.x & 63);
  int e0 = a[2*L], e1 = a[2*L + 1];
  for (int kk = 2; kk <= 128; kk <<= 1) {
    for (int jj = kk >> 1; jj >= 2; jj >>= 1) {
      int pl = jj >> 1;
      int o0 = __shfl_xor(e0, pl);
      int o1 = __shfl_xor(e1, pl);
      bool upper = (L & pl) != 0;
      bool up = ((2*L) & kk) == 0;
      if (up != upper) { e0 = min(e0, o0); e1 = min(e1, o1); }
      else             { e0 = max(e0, o0); e1 = max(e1, o1); }
    }
    bool up = ((2*L) & kk) == 0;
    int lo = min(e0, e1), hi = max(e0, e1);
    e0 = up ? lo : hi; e1 = up ? hi : lo;
  }
  a[2*L] = e0; a[2*L + 1] = e1;
}

// ============ K34: FUSED select + SPLIT-N A assembly (x2) + m blocks ============
// r13: Asel's A-phase (512 n-iters/thread serial) dominated at ~0.9 block/CU.
// Split-N x2: two blocks per (img,tile), each sums 256 of 512 points into
// fp32 partial ad2[half] (select redundantly recomputed — parallel, so per-
// block serial time halves). Partial combine + OUT_A emission move to k_inv_m
// (which loads the full 100x100 anyway). Diag partials never read (inv
// special-cases r==col).
__global__ __launch_bounds__(256) void k_Asel(const float* __restrict__ pts,
                                              const double* __restrict__ vd,
                                              float* __restrict__ out,
                                              float* __restrict__ ad,
                                              float* __restrict__ vm) {
  __shared__ AselU u;
  __shared__ int selFinal[128];         // survives the union switch se -> ka
  int bid = blockIdx.x;                 // img*56 + tile*2 + half  |  m blocks
  if (bid >= BB*56) { m_units(pts, out, MU_VP + (bid - BB*56)*MU_PER, MU_PER); return; }
  int img = bid / 56;
  int rem56 = bid - img*56;
  int tile = rem56 >> 1;
  int half = rem56 & 1;
  bool emit = (tile == 0) && (half == 0);
  int tid = threadIdx.x;
  int wv = tid >> 6;
  int lane = tid & 63;
  int hc = tid >> 3;                    // histogram copy (8 lanes per copy)

  // ================= select phase (LDS as u.se) =================
  for (int t = 0; t < 16; ++t) {
    int g = t*256 + tid;
    // deterministic fixed-order sum of the four split-K partials
    float v = (float)(((vd[img*GG + g] + vd[BB*GG + img*GG + g])
                     + vd[2*BB*GG + img*GG + g]) + vd[3*BB*GG + img*GG + g]);
    if (emit) out[OUT_V + img*GG + g] = fmaxf(v, 1e-6f);
    int w = __float_as_int(v);
    u.se.ku[g] = (w < 0) ? ~(unsigned)w : ((unsigned)w | 0x80000000u);
  }
  if (tid == 0) {
    u.se.sRem = 100; u.se.sPref = 0u; u.se.sMask = 0u;
    u.se.sCGt = 0; u.se.sCEq = 0;
  }
  // ---- 4 radix passes, MSB first ----
  for (int shift = 24; shift >= 0; shift -= 8) {
    for (int s = tid; s < 32*257; s += 256) (&u.se.hist[0][0])[s] = 0;
    __syncthreads();                    // ku/state ready, hist zeroed
    unsigned mask = u.se.sMask, pref = u.se.sPref;
    for (int t = 0; t < 16; ++t) {
      unsigned k = u.se.ku[t*256 + tid];
      if ((k & mask) == pref)
        atomicAdd(&u.se.hist[hc][(k >> shift) & 255u], 1u);
    }
    __syncthreads();
    unsigned tot = 0;
    #pragma unroll
    for (int c = 0; c < 32; ++c) tot += u.se.hist[c][tid];  // banks (c+tid)%32: conflict-free
    // wave-level inclusive SUFFIX scan over the 64 bins this wave owns
    unsigned val = tot;
    #pragma unroll
    for (int off = 1; off < 64; off <<= 1) {
      unsigned o = (unsigned)__shfl_down((int)val, off);
      if (lane + off < 64) val += o;
    }
    if (lane == 0) u.se.wq[wv] = val;   // whole-wave total
    __syncthreads();
    unsigned suf = val;                 // + totals of higher waves (higher digits)
    for (int w2 = wv + 1; w2 < 4; ++w2) suf += u.se.wq[w2];
    unsigned rem = u.se.sRem;
    unsigned sgt = suf - tot;           // count with digit strictly greater
    if (suf >= rem && sgt < rem) { u.se.sPickB = (unsigned)tid; u.se.sPickRem = rem - sgt; }
    __syncthreads();
    if (tid == 0) {
      u.se.sPref |= u.se.sPickB << shift;
      u.se.sMask |= 255u << shift;
      u.se.sRem   = u.se.sPickRem;
    }
    __syncthreads();
  }
  // ---- collect: all k > T, plus r smallest-index ties (k == T) ----
  unsigned T = u.se.sPref;              // exact 100th-largest fp32 key
  for (int t = 0; t < 16; ++t) {
    int g = t*256 + tid;
    unsigned k = u.se.ku[g];
    if (k > T) {
      unsigned p = atomicAdd(&u.se.sCGt, 1u);   // p <= 98 always
      selFinal[p] = g;
    } else if (k == T) {
      unsigned p = atomicAdd(&u.se.sCEq, 1u);
      if (p < 128) u.se.tie[p] = g;     // >128 exact-equal boundary: pathological
    }
  }
  __syncthreads();
  unsigned cgt = u.se.sCGt, ceq = u.se.sCEq, r = u.se.sRem;
  if (tid < 128 && tid >= (int)((ceq < 128u) ? ceq : 128u)) u.se.tie[tid] = 0x7fffffff;
  __syncthreads();
  if (tid < 64) wave_sort128(u.se.tie);          // ties ascending by index
  __syncthreads();
  if (tid < (int)r) selFinal[cgt + tid] = u.se.tie[tid];
  if (tid >= MM && tid < 128) selFinal[tid] = 0x7fffffff;
  __syncthreads();
  if (tid < 64) wave_sort128(selFinal);          // final Minds ascending
  __syncthreads();
  if (emit && tid < MM) {
    int mi = selFinal[tid];
    out[OUT_MI + img*MM + tid] = (float)mi;      // whole out buffer is float32
    float vsel = (float)(((vd[img*GG + mi] + vd[BB*GG + img*GG + mi])
                        + vd[2*BB*GG + img*GG + mi]) + vd[3*BB*GG + img*GG + mi]);
    vm[img*MM + tid] = fmaxf(vsel, 1e-6f) + 1e-10f;  // ref fp32 semantics
  }
  __syncthreads();                               // done with u.se before ka overwrite

  // ================= A phase (LDS as u.ka): points [half*256, half*256+256) =================
  int it = 0, trem = tile;
  while (trem >= 7 - it) { trem -= 7 - it; ++it; }
  int jt = it + trem;
  int i0 = it*16, j0 = jt*16;
  int tj = tid & 15, ti = tid >> 4;
  int i = i0 + ti, j = j0 + tj;
  const float CM = (float)(1.0/(2.0*M_PI*128.0));
  const float C1 = (float)(1.0/(2.0*M_PI*128.0));   // g1 scale (2*pi*2*sigma2)
  const float C2 = (float)(1.0/(2.0*M_PI*96.0));    // h scale (2*pi*s2)
  for (int s = tid; s < NN; s += 256) {
    u.ka.px[s] = pts[(img*NN + s)*2 + 0];
    u.ka.py[s] = pts[(img*NN + s)*2 + 1];
  }
  if (tid < 16) {
    int gi = i0 + tid; if (gi > 99) gi = 99;
    int mi = selFinal[gi];
    u.ka.cxi[tid] = 8.0f*(mi & 63) + 4.0f;
    u.ka.cyi[tid] = 8.0f*(mi >> 6) + 4.0f;
  } else if (tid < 32) {
    int rr = tid - 16;
    int gj = j0 + rr; if (gj > 99) gj = 99;
    int mj = selFinal[gj];
    u.ka.cxj[rr] = 8.0f*(mj & 63) + 4.0f;
    u.ka.cyj[rr] = 8.0f*(mj >> 6) + 4.0f;
  }
  float aV = 0.0f, aM = 0.0f;
  for (int nc = half*256; nc < half*256 + 256; nc += 128) {
    __syncthreads();
    for (int s = tid; s < 16*128; s += 256) {
      int row = s >> 7, n = s & 127;
      float x = u.ka.px[nc + n], y = u.ka.py[nc + n];
      float fxi = x - u.ka.cxi[row], fyi = y - u.ka.cyi[row];
      u.ka.sxi[row][n] = fxi; u.ka.syi[row][n] = fyi;
      u.ka.sti[row][n] = __expf((fxi*fxi + fyi*fyi)*(-0.5f/128.0f))*CM;
      float fxj = x - u.ka.cxj[row], fyj = y - u.ka.cyj[row];
      u.ka.sxj[row][n] = fxj; u.ka.syj[row][n] = fyj;
      u.ka.stj[row][n] = __expf((fxj*fxj + fyj*fyj)*(-0.5f/128.0f))*CM;
    }
    __syncthreads();
    #pragma unroll 4
    for (int n = 0; n < 128; ++n) {
      float xi = u.ka.sxi[ti][n], yi = u.ka.syi[ti][n], tii = u.ka.sti[ti][n];
      float xj = u.ka.sxj[tj][n], yj = u.ka.syj[tj][n], tjj = u.ka.stj[tj][n];
      float ddx = xj - xi, ddy = yj - yi;
      float df = ddx*ddx + ddy*ddy;
      float sx = 0.5f*(xi + xj), sy = 0.5f*(yi + yj);
      float af = sx*sx + sy*sy;
      float g1 = __expf(df*(-0.5f/128.0f))*C1;
      float h  = __expf(af*(-0.5f/96.0f))*C2;
      aV += g1 + g1*h;
      aM += tii*tjj;
    }
  }
  if (i < 100 && j < 100) {
    float val = (i == j) ? 1e-10f : (float)((double)aV - (double)aM);
    ad[((half*BB + img)*MM + i)*MM + j] = val;
    if (it != jt) {                     // mirror (diag tiles cover both in-tile)
      ad[((half*BB + img)*MM + j)*MM + i] = val;
    }
  }
}

// ============ K5: FP32 GJ inversion, 512-THREAD blocks; sums ad2 partials, emits OUT_A ============
#define PRS 130
__global__ __launch_bounds__(512)
void k_inv_m(const float* __restrict__ ad,
             const float* __restrict__ vm,
             const float* __restrict__ pts,
             float* __restrict__ out) {
  __shared__ float S[128*17];           //  8,704 B
  __shared__ float Pr[16*PRS];          //  8,320 B
  __shared__ float svm[112];            //    448 B  -> total ~17.5 KB
  if (blockIdx.x >= BB) {
    m_units512(pts, out, MU_VP + MU_AS + ((int)blockIdx.x - BB)*MU_PER, MU_PER);
    return;
  }
  int img = blockIdx.x;
  int tx = threadIdx.x & 31, ty = threadIdx.x >> 5;   // ty in [0,16), tx in [0,32)
  float C[7][4];
  if (threadIdx.x < 100) svm[threadIdx.x] = vm[img*MM + threadIdx.x];
  // init C = (ad2[0]+ad2[1]) + diag(vM); also emit OUT_A (sum; diag 1e-10)
  #pragma unroll
  for (int a = 0; a < 7; ++a) {
    int r = ty + 16*a;
    #pragma unroll
    for (int b = 0; b < 4; ++b) {
      int col = tx + 32*b;
      float v2 = 0.0f;
      if (r < 100 && col < 100) {
        if (r == col) {
          v2 = 1e-10f + vm[img*MM + r];
          out[OUT_A + (img*MM + r)*MM + col] = 1e-10f;
        } else {
          float s = ad[(img*MM + r)*MM + col] + ad[((BB + img)*MM + r)*MM + col];
          v2 = s;
          out[OUT_A + (img*MM + r)*MM + col] = s;
        }
      }
      C[a][b] = v2;
    }
  }
  for (int p = 0; p < 7; ++p) {
    int k0 = p*16;
    int nbp = (p == 6) ? 4 : 16;
    // ---- P1: stage panel-col strip S + panel rows Pr (phase-start values)
    {
      int bp = p >> 1;                   // chunk containing panel p
      bool mine = ((tx >> 4) == (p & 1));// my half of that chunk
      int cq = tx & 15;                  // panel-local column
      #pragma unroll
      for (int a = 0; a < 7; ++a) {
        int r = ty + 16*a;
        if (mine) {
          float val = 0.0f;
          #pragma unroll
          for (int b = 0; b < 4; ++b) if (b == bp) val = C[a][b];
          S[r*17 + cq] = (r < 100 && cq < nbp) ? val : 0.0f;
        }
      }
    }
    {
      // panel rows k0..k0+15 owned by a==p: thread (ty,tx) holds C[p][b]
      float pv[4];
      #pragma unroll
      for (int b = 0; b < 4; ++b) pv[b] = 0.0f;
      #pragma unroll
      for (int a = 0; a < 7; ++a) {
        #pragma unroll
        for (int b = 0; b < 4; ++b) if (a == p) pv[b] = C[a][b];
      }
      #pragma unroll
      for (int b = 0; b < 4; ++b) Pr[ty*PRS + tx + 32*b] = pv[b];
    }
    __syncthreads();                                   // B1
    // ---- P2: wave 0 register-resident strip factorization (no pivoting)
    if (threadIdx.x < 64) {
      int lane = threadIdx.x;
      float P0[16], P1[16];
      #pragma unroll
      for (int c = 0; c < 16; ++c) {
        P0[c] = S[lane*17 + c];
        P1[c] = (lane + 64 < 112) ? S[(lane + 64)*17 + c] : 0.0f;
      }
      #pragma unroll
      for (int kk = 0; kk < 16; ++kk) {
        if (kk < nbp) {
          int kg = k0 + kk;
          int r1 = lane + 64;
          bool khigh = kg >= 64; int kl = kg & 63;
          float pivinv = 1.0f / flt_readlane(khigh ? P1[kk] : P0[kk], kl);
          float pr[16];
          #pragma unroll
          for (int c = 0; c < 16; ++c) {
            float pv = flt_readlane(khigh ? P1[c] : P0[c], kl);
            pr[c] = (c == kk) ? pivinv : pv*pivinv;
          }
          {
            float f = P0[kk];
            if (lane == kg) {
              #pragma unroll
              for (int c = 0; c < 16; ++c) P0[c] = pr[c];
            } else {
              #pragma unroll
              for (int c = 0; c < 16; ++c) P0[c] = ((c == kk) ? 0.0f : P0[c]) - f*pr[c];
            }
          }
          {
            float f = P1[kk];
            if (r1 == kg) {
              #pragma unroll
              for (int c = 0; c < 16; ++c) P1[c] = pr[c];
            } else {
              #pragma unroll
              for (int c = 0; c < 16; ++c) P1[c] = ((c == kk) ? 0.0f : P1[c]) - f*pr[c];
            }
          }
        }
      }
      #pragma unroll
      for (int c = 0; c < 16; ++c) {
        S[lane*17 + c] = P0[c];
        if (lane + 64 < 112) S[(lane + 64)*17 + c] = P1[c];
      }
    }
    __syncthreads();                                   // B2
    // ---- P3: mask C in REGISTERS, trailing rank-16 update, panel-col writeback
    #pragma unroll
    for (int a = 0; a < 7; ++a) {
      int r = ty + 16*a;
      bool prow_ = (r >= k0) && (r < k0 + 16);
      #pragma unroll
      for (int b = 0; b < 4; ++b) {
        int col = tx + 32*b;
        if (r >= 100 || (col >> 4) == p || prow_) C[a][b] = 0.0f;
      }
    }
    #pragma unroll 4
    for (int t = 0; t < 16; ++t) {
      bool tok = (t < nbp);
      float bt[4], sa[7];
      #pragma unroll
      for (int b = 0; b < 4; ++b) bt[b] = tok ? Pr[t*PRS + tx + 32*b] : 0.0f;
      #pragma unroll
      for (int a = 0; a < 7; ++a) sa[a] = S[(ty + 16*a)*17 + t];
      #pragma unroll
      for (int a = 0; a < 7; ++a)
        #pragma unroll
        for (int b = 0; b < 4; ++b) C[a][b] += sa[a]*bt[b];
    }
    #pragma unroll
    for (int a = 0; a < 7; ++a) {
      int r = ty + 16*a;
      #pragma unroll
      for (int b = 0; b < 4; ++b) {
        int col = tx + 32*b;
        if ((col >> 4) == p) C[a][b] = S[r*17 + (col & 15)];
      }
    }
    __syncthreads();                                   // B3 (WAR on S/Pr)
  }
  // Bm = Dv^{-1} - X
  #pragma unroll
  for (int a = 0; a < 7; ++a) {
    int r = ty + 16*a; if (r >= 100) continue;
    float dinv = 1.0f / svm[r];
    #pragma unroll
    for (int b = 0; b < 4; ++b) {
      int col = tx + 32*b; if (col >= 100) continue;
      float val = ((col == r) ? dinv : 0.0f) - C[a][b];
      out[OUT_B + (img*MM + r)*MM + col] = val;
    }
  }
}

extern "C" void kernel_launch(void* const* d_in, const int* in_sizes, int n_in,
                              void* d_out, int out_size, void* d_ws, size_t ws_size,
                              hipStream_t stream) {
  const float* pts = (const float*)d_in[0];
  float* out = (float*)d_out;
  char* ws = (char*)d_ws;
  double* vd  = (double*)(ws + OFF_VD);
  float* vmd = (float*)(ws + OFF_VM);
  float* ad  = (float*)(ws + OFF_AD);

  hipLaunchKernelGGL(k_vpart, dim3(BB*64 + MU_VP/MU_PER), dim3(256), 0, stream, pts, vd, out);
  hipLaunchKernelGGL(k_Asel, dim3(BB*56 + MU_AS/MU_PER), dim3(256), 0, stream, pts, vd, out, ad, vmd);
  hipLaunchKernelGGL(k_inv_m, dim3(BB + MU_IV/MU_PER), dim3(512), 0, stream, ad, vmd, pts, out);
}

// Round 16
// 188.516 us; speedup vs baseline: 1.1235x; 1.0100x over previous
//
#include <hip/hip_runtime.h>
#include <math.h>

#ifndef M_PI
#define M_PI 3.14159265358979323846
#endif

#define BB 8
#define NN 512
#define KK 64
#define GG 4096
#define MM 100

// ---------------- workspace layout (byte offsets) ----------------
// vd: FOUR fp64 partial quarters (split-K x4); ad: TWO fp32 partial halves
#define SZ_VD    (BB*GG*8u*4u)
#define OFF_VD   0u
#define SZ_VM    (BB*MM*4u)
#define OFF_VM   (OFF_VD + SZ_VD)
#define SZ_AD    (BB*MM*MM*4u*2u)
#define OFF_AD   (OFF_VM + SZ_VM)
#define OFF_MIND (OFF_AD + SZ_AD)

// ---------------- output layout (float element offsets) ----------------
#define OUT_M  0
#define OUT_V  (BB*NN*GG)               // 16,777,216
#define OUT_A  (OUT_V + BB*GG)          // 16,809,984
#define OUT_B  (OUT_A + BB*MM*MM)      // 16,889,984
#define OUT_MI (OUT_B + BB*MM*MM)      // 16,969,984

// ---------------- m-unit allocation across dispatches ----------------
// r15: select un-fused from A (it was redundantly recomputed in all 448
// A-blocks = the majority of the fused kernel). 4 dispatches, each m-covered.
#define MU_PER 8
#define MU_VP 4096            // with k_vpart   -> 512 m-blocks
#define MU_SE 1024            // with k_select  -> 128 m-blocks
#define MU_KA 2048            // with k_A       -> 256 m-blocks
#define MU_IV 9216            // with k_inv_m   -> 1152 m-blocks

__device__ __forceinline__ void m_units(const float* __restrict__ pts,
                                        float* __restrict__ out, int u0, int cnt) {
  const float CM = (float)(1.0/(2.0*M_PI*128.0));
  for (int k = 0; k < cnt; ++k) {
    int u = u0 + k;
    int t = u*256 + (int)threadIdx.x;
    int e = t << 2;
    int img = e >> 21;
    int rem = e & ((1 << 21) - 1);
    int n = rem >> 12;
    int g = rem & 4095;
    int iy = g >> 6, ix = g & 63;       // e%4==0 -> ix%4==0
    float x = pts[(img*NN + n)*2 + 0];
    float y = pts[(img*NN + n)*2 + 1];
    float dy = y - (8.0f*iy + 4.0f);
    float ey = __expf(dy*dy*(-0.5f/128.0f));
    float4 r;
    float dx0 = x - (8.0f*ix + 4.0f);
    float dx1 = x - (8.0f*(ix+1) + 4.0f);
    float dx2 = x - (8.0f*(ix+2) + 4.0f);
    float dx3 = x - (8.0f*(ix+3) + 4.0f);
    r.x = ey*__expf(dx0*dx0*(-0.5f/128.0f))*CM;
    r.y = ey*__expf(dx1*dx1*(-0.5f/128.0f))*CM;
    r.z = ey*__expf(dx2*dx2*(-0.5f/128.0f))*CM;
    r.w = ey*__expf(dx3*dx3*(-0.5f/128.0f))*CM;
    *reinterpret_cast<float4*>(&out[OUT_M + e]) = r;
  }
}

// 512-thread variant: cnt units, 2 units per pass (512 thr x float4 = 2 units)
__device__ __forceinline__ void m_units512(const float* __restrict__ pts,
                                           float* __restrict__ out, int u0, int cnt) {
  const float CM = (float)(1.0/(2.0*M_PI*128.0));
  for (int k = 0; k < cnt/2; ++k) {
    int t = u0*256 + k*512 + (int)threadIdx.x;
    int e = t << 2;
    int img = e >> 21;
    int rem = e & ((1 << 21) - 1);
    int n = rem >> 12;
    int g = rem & 4095;
    int iy = g >> 6, ix = g & 63;
    float x = pts[(img*NN + n)*2 + 0];
    float y = pts[(img*NN + n)*2 + 1];
    float dy = y - (8.0f*iy + 4.0f);
    float ey = __expf(dy*dy*(-0.5f/128.0f));
    float4 r;
    float dx0 = x - (8.0f*ix + 4.0f);
    float dx1 = x - (8.0f*(ix+1) + 4.0f);
    float dx2 = x - (8.0f*(ix+2) + 4.0f);
    float dx3 = x - (8.0f*(ix+3) + 4.0f);
    r.x = ey*__expf(dx0*dx0*(-0.5f/128.0f))*CM;
    r.y = ey*__expf(dx1*dx1*(-0.5f/128.0f))*CM;
    r.z = ey*__expf(dx2*dx2*(-0.5f/128.0f))*CM;
    r.w = ey*__expf(dx3*dx3*(-0.5f/128.0f))*CM;
    *reinterpret_cast<float4*>(&out[OUT_M + e]) = r;
  }
}

__device__ __forceinline__ float flt_readlane(float v, int l) {
  return __int_as_float(__builtin_amdgcn_readlane(__float_as_int(v), l));
}

// ============ K2: v — SPLIT-K x4 + recurrence exp tables + double2 LDS reads ============
__global__ __launch_bounds__(256) void k_vpart(const float* __restrict__ pts,
                                               double* __restrict__ vd,
                                               float* __restrict__ out) {
  __shared__ double sEy2[16][66], sEy3[16][66], sEx2[16][66], sEx3[16][66];
  __shared__ float px[128], py[128];
  int bid = blockIdx.x;                 // (img*16+tile)*4+quarter  |  m blocks
  if (bid >= BB*64) { m_units(pts, out, (bid - BB*64)*MU_PER, MU_PER); return; }
  int quarter = bid & 3;
  int rem = bid >> 2;
  int tile = rem & 15;
  int img = rem >> 4;
  int iy0 = (tile >> 2) << 4;
  int ix0 = (tile & 3) << 4;
  int tx = threadIdx.x & 15, ty = threadIdx.x >> 4;
  int n = threadIdx.x & 63;             // point-in-chunk this thread fills
  int tbl = threadIdx.x >> 6;           // wave -> table (wave-uniform)
  if (threadIdx.x < 128) {
    px[threadIdx.x] = pts[(img*NN + quarter*128 + threadIdx.x)*2 + 0];
    py[threadIdx.x] = pts[(img*NN + quarter*128 + threadIdx.x)*2 + 1];
  }
  const double alpha = (tbl & 1) ? (1.0/128.0) : (0.5/96.0);
  const double Q = exp(-128.0*alpha);   // exp(-2/3) or exp(-1), hoisted
  const int base = (tbl >= 2) ? ix0 : iy0;
  double* dst = (tbl == 0) ? &sEy2[0][0] : (tbl == 1) ? &sEy3[0][0]
              : (tbl == 2) ? &sEx2[0][0] : &sEx3[0][0];
  double aV = 0.0, aM = 0.0;
  for (int kc = 0; kc < 2; ++kc) {
    int nbl = kc << 6;
    __syncthreads();                    // WAR on LDS (and px/py ready on kc=0)
    {
      int nn = nbl + n;
      double coord = (tbl >= 2) ? (double)px[nn] : (double)py[nn];
      double d0 = coord - (8.0*base + 4.0);
      double E = exp(-alpha*d0*d0);     // row 0 value
      double R = exp(alpha*(16.0*d0 - 64.0));
      #pragma unroll
      for (int row = 0; row < 16; ++row) {
        dst[row*66 + n] = E;
        E *= R; R *= Q;
      }
    }
    __syncthreads();
    #pragma unroll 8
    for (int n2 = 0; n2 < 64; n2 += 2) {
      double2 y2 = *reinterpret_cast<const double2*>(&sEy2[ty][n2]);
      double2 x2 = *reinterpret_cast<const double2*>(&sEx2[tx][n2]);
      double2 y3 = *reinterpret_cast<const double2*>(&sEy3[ty][n2]);
      double2 x3 = *reinterpret_cast<const double2*>(&sEx3[tx][n2]);
      aV += y2.x*x2.x; aV += y2.y*x2.y;  // same sequential order as scalar loop
      aM += y3.x*x3.x; aM += y3.y*x3.y;
    }
  }
  const double CTV = 1.0/((2.0*M_PI*96.0)*(2.0*M_PI*128.0));
  const double CM2 = 1.0/((2.0*M_PI*128.0)*(2.0*M_PI*128.0));
  vd[quarter*(BB*GG) + img*GG + (iy0 + ty)*KK + ix0 + tx] = CTV*aV - CM2*aM;
}

// ---------------- single-wave bitonic sort of 128 ints (2 elems/lane) ----------------
__device__ __forceinline__ void wave_sort128(int* a) {
  int L = (int)(threadIdx.x & 63);
  int e0 = a[2*L], e1 = a[2*L + 1];
  for (int kk = 2; kk <= 128; kk <<= 1) {
    for (int jj = kk >> 1; jj >= 2; jj >>= 1) {
      int pl = jj >> 1;
      int o0 = __shfl_xor(e0, pl);
      int o1 = __shfl_xor(e1, pl);
      bool upper = (L & pl) != 0;
      bool up = ((2*L) & kk) == 0;
      if (up != upper) { e0 = min(e0, o0); e1 = min(e1, o1); }
      else             { e0 = max(e0, o0); e1 = max(e1, o1); }
    }
    bool up = ((2*L) & kk) == 0;
    int lo = min(e0, e1), hi = max(e0, e1);
    e0 = up ? lo : hi; e1 = up ? hi : lo;
  }
  a[2*L] = e0; a[2*L + 1] = e1;
}

// ============ K3: top-100 select — ONCE per image (8 blocks) + m blocks ============
// r15: un-fused from k_A. The select (4 radix passes + sorts, ~10-12 us/block)
// was redundantly executed in all 448 A-blocks at 2 blocks/CU residency.
// Here it runs once per image; A reads minds from ws.
__global__ __launch_bounds__(256) void k_select(const double* __restrict__ vd,
                                               float* __restrict__ out,
                                               int* __restrict__ minds,
                                               float* __restrict__ vm,
                                               const float* __restrict__ pts) {
  __shared__ unsigned int ku[GG];              // 16 KB fp32 sortable keys
  __shared__ unsigned int hist[32][257];       // 32 copies, bank-spread
  __shared__ unsigned int wq[4];
  __shared__ unsigned int sPref, sMask;
  __shared__ unsigned int sRem, sPickB, sPickRem, sCGt, sCEq;
  __shared__ int tie[128];
  __shared__ int selFinal[128];
  int bid = blockIdx.x;
  if (bid >= BB) { m_units(pts, out, MU_VP + (bid - BB)*MU_PER, MU_PER); return; }
  int img = bid;
  int tid = threadIdx.x;
  int wv = tid >> 6;
  int lane = tid & 63;
  int hc = tid >> 3;                    // histogram copy (8 lanes per copy)

  for (int t = 0; t < 16; ++t) {
    int g = t*256 + tid;
    // deterministic fixed-order sum of the four split-K partials
    float v = (float)(((vd[img*GG + g] + vd[BB*GG + img*GG + g])
                     + vd[2*BB*GG + img*GG + g]) + vd[3*BB*GG + img*GG + g]);
    out[OUT_V + img*GG + g] = fmaxf(v, 1e-6f);
    int w = __float_as_int(v);
    ku[g] = (w < 0) ? ~(unsigned)w : ((unsigned)w | 0x80000000u);
  }
  if (tid == 0) {
    sRem = 100; sPref = 0u; sMask = 0u;
    sCGt = 0; sCEq = 0;
  }
  // ---- 4 radix passes, MSB first ----
  for (int shift = 24; shift >= 0; shift -= 8) {
    for (int s = tid; s < 32*257; s += 256) (&hist[0][0])[s] = 0;
    __syncthreads();                    // ku/state ready, hist zeroed
    unsigned mask = sMask, pref = sPref;
    for (int t = 0; t < 16; ++t) {
      unsigned k = ku[t*256 + tid];
      if ((k & mask) == pref)
        atomicAdd(&hist[hc][(k >> shift) & 255u], 1u);
    }
    __syncthreads();
    unsigned tot = 0;
    #pragma unroll
    for (int c = 0; c < 32; ++c) tot += hist[c][tid];  // banks spread: conflict-free
    // wave-level inclusive SUFFIX scan over the 64 bins this wave owns
    unsigned val = tot;
    #pragma unroll
    for (int off = 1; off < 64; off <<= 1) {
      unsigned o = (unsigned)__shfl_down((int)val, off);
      if (lane + off < 64) val += o;
    }
    if (lane == 0) wq[wv] = val;        // whole-wave total
    __syncthreads();
    unsigned suf = val;                 // + totals of higher waves (higher digits)
    for (int w2 = wv + 1; w2 < 4; ++w2) suf += wq[w2];
    unsigned rem = sRem;
    unsigned sgt = suf - tot;           // count with digit strictly greater
    if (suf >= rem && sgt < rem) { sPickB = (unsigned)tid; sPickRem = rem - sgt; }
    __syncthreads();
    if (tid == 0) {
      sPref |= sPickB << shift;
      sMask |= 255u << shift;
      sRem   = sPickRem;
    }
    __syncthreads();
  }
  // ---- collect: all k > T, plus r smallest-index ties (k == T) ----
  unsigned T = sPref;                   // exact 100th-largest fp32 key
  for (int t = 0; t < 16; ++t) {
    int g = t*256 + tid;
    unsigned k = ku[g];
    if (k > T) {
      unsigned p = atomicAdd(&sCGt, 1u);        // p <= 98 always
      selFinal[p] = g;
    } else if (k == T) {
      unsigned p = atomicAdd(&sCEq, 1u);
      if (p < 128) tie[p] = g;          // >128 exact-equal boundary: pathological
    }
  }
  __syncthreads();
  unsigned cgt = sCGt, ceq = sCEq, r = sRem;
  if (tid < 128 && tid >= (int)((ceq < 128u) ? ceq : 128u)) tie[tid] = 0x7fffffff;
  __syncthreads();
  if (tid < 64) wave_sort128(tie);               // ties ascending by index
  __syncthreads();
  if (tid < (int)r) selFinal[cgt + tid] = tie[tid];
  if (tid >= MM && tid < 128) selFinal[tid] = 0x7fffffff;
  __syncthreads();
  if (tid < 64) wave_sort128(selFinal);          // final Minds ascending
  __syncthreads();
  if (tid < MM) {
    int mi = selFinal[tid];
    minds[img*MM + tid] = mi;
    out[OUT_MI + img*MM + tid] = (float)mi;      // whole out buffer is float32
    float vsel = (float)(((vd[img*GG + mi] + vd[BB*GG + img*GG + mi])
                        + vd[2*BB*GG + img*GG + mi]) + vd[3*BB*GG + img*GG + mi]);
    vm[img*MM + tid] = fmaxf(vsel, 1e-6f) + 1e-10f;  // ref fp32 semantics
  }
}

// ============ K4: A assembly — SPLIT-N x2, minds from ws + m blocks ============
__global__ __launch_bounds__(256) void k_A(const float* __restrict__ pts,
                                           const int* __restrict__ minds,
                                           float* __restrict__ out,
                                           float* __restrict__ ad) {
  __shared__ float sxi[16][130], syi[16][130], sti[16][130];
  __shared__ float sxj[16][130], syj[16][130], stj[16][130];
  __shared__ float px[256], py[256];
  __shared__ float cxi[16], cyi[16], cxj[16], cyj[16];
  int bid = blockIdx.x;                 // img*56 + tile*2 + half  |  m blocks
  if (bid >= BB*56) { m_units(pts, out, MU_VP + MU_SE + (bid - BB*56)*MU_PER, MU_PER); return; }
  int img = bid / 56;
  int rem56 = bid - img*56;
  int tile = rem56 >> 1;
  int half = rem56 & 1;
  int tid = threadIdx.x;
  int it = 0, trem = tile;
  while (trem >= 7 - it) { trem -= 7 - it; ++it; }
  int jt = it + trem;
  int i0 = it*16, j0 = jt*16;
  int tj = tid & 15, ti = tid >> 4;
  int i = i0 + ti, j = j0 + tj;
  const float CM = (float)(1.0/(2.0*M_PI*128.0));
  const float C1 = (float)(1.0/(2.0*M_PI*128.0));   // g1 scale (2*pi*2*sigma2)
  const float C2 = (float)(1.0/(2.0*M_PI*96.0));    // h scale (2*pi*s2)
  if (tid < 256) {                                  // this block's 256 points
    px[tid] = pts[(img*NN + half*256 + tid)*2 + 0];
    py[tid] = pts[(img*NN + half*256 + tid)*2 + 1];
  }
  if (tid < 16) {
    int gi = i0 + tid; if (gi > 99) gi = 99;
    int mi = minds[img*MM + gi];
    cxi[tid] = 8.0f*(mi & 63) + 4.0f;
    cyi[tid] = 8.0f*(mi >> 6) + 4.0f;
  } else if (tid < 32) {
    int rr = tid - 16;
    int gj = j0 + rr; if (gj > 99) gj = 99;
    int mj = minds[img*MM + gj];
    cxj[rr] = 8.0f*(mj & 63) + 4.0f;
    cyj[rr] = 8.0f*(mj >> 6) + 4.0f;
  }
  float aV = 0.0f, aM = 0.0f;
  for (int c2 = 0; c2 < 256; c2 += 128) {
    __syncthreads();
    for (int s = tid; s < 16*128; s += 256) {
      int row = s >> 7, n = s & 127;
      float x = px[c2 + n], y = py[c2 + n];
      float fxi = x - cxi[row], fyi = y - cyi[row];
      sxi[row][n] = fxi; syi[row][n] = fyi;
      sti[row][n] = __expf((fxi*fxi + fyi*fyi)*(-0.5f/128.0f))*CM;
      float fxj = x - cxj[row], fyj = y - cyj[row];
      sxj[row][n] = fxj; syj[row][n] = fyj;
      stj[row][n] = __expf((fxj*fxj + fyj*fyj)*(-0.5f/128.0f))*CM;
    }
    __syncthreads();
    #pragma unroll 4
    for (int n = 0; n < 128; ++n) {
      float xi = sxi[ti][n], yi = syi[ti][n], tii = sti[ti][n];
      float xj = sxj[tj][n], yj = syj[tj][n], tjj = stj[tj][n];
      float ddx = xj - xi, ddy = yj - yi;
      float df = ddx*ddx + ddy*ddy;
      float sx = 0.5f*(xi + xj), sy = 0.5f*(yi + yj);
      float af = sx*sx + sy*sy;
      float g1 = __expf(df*(-0.5f/128.0f))*C1;
      float h  = __expf(af*(-0.5f/96.0f))*C2;
      aV += g1 + g1*h;
      aM += tii*tjj;
    }
  }
  if (i < 100 && j < 100) {
    float val = (i == j) ? 1e-10f : (float)((double)aV - (double)aM);
    ad[((half*BB + img)*MM + i)*MM + j] = val;
    if (it != jt) {                     // mirror (diag tiles cover both in-tile)
      ad[((half*BB + img)*MM + j)*MM + i] = val;
    }
  }
}

// ============ K5: FP32 GJ inversion, 512-THREAD blocks; sums ad2 partials, emits OUT_A ============
#define PRS 130
__global__ __launch_bounds__(512)
void k_inv_m(const float* __restrict__ ad,
             const float* __restrict__ vm,
             const float* __restrict__ pts,
             float* __restrict__ out) {
  __shared__ float S[128*17];           //  8,704 B
  __shared__ float Pr[16*PRS];          //  8,320 B
  __shared__ float svm[112];            //    448 B  -> total ~17.5 KB
  if (blockIdx.x >= BB) {
    m_units512(pts, out, MU_VP + MU_SE + MU_KA + ((int)blockIdx.x - BB)*MU_PER, MU_PER);
    return;
  }
  int img = blockIdx.x;
  int tx = threadIdx.x & 31, ty = threadIdx.x >> 5;   // ty in [0,16), tx in [0,32)
  float C[7][4];
  if (threadIdx.x < 100) svm[threadIdx.x] = vm[img*MM + threadIdx.x];
  // init C = (ad2[0]+ad2[1]) + diag(vM); also emit OUT_A (sum; diag 1e-10)
  #pragma unroll
  for (int a = 0; a < 7; ++a) {
    int r = ty + 16*a;
    #pragma unroll
    for (int b = 0; b < 4; ++b) {
      int col = tx + 32*b;
      float v2 = 0.0f;
      if (r < 100 && col < 100) {
        if (r == col) {
          v2 = 1e-10f + vm[img*MM + r];
          out[OUT_A + (img*MM + r)*MM + col] = 1e-10f;
        } else {
          float s = ad[(img*MM + r)*MM + col] + ad[((BB + img)*MM + r)*MM + col];
          v2 = s;
          out[OUT_A + (img*MM + r)*MM + col] = s;
        }
      }
      C[a][b] = v2;
    }
  }
  for (int p = 0; p < 7; ++p) {
    int k0 = p*16;
    int nbp = (p == 6) ? 4 : 16;
    // ---- P1: stage panel-col strip S + panel rows Pr (phase-start values)
    {
      int bp = p >> 1;                   // chunk containing panel p
      bool mine = ((tx >> 4) == (p & 1));// my half of that chunk
      int cq = tx & 15;                  // panel-local column
      #pragma unroll
      for (int a = 0; a < 7; ++a) {
        int r = ty + 16*a;
        if (mine) {
          float val = 0.0f;
          #pragma unroll
          for (int b = 0; b < 4; ++b) if (b == bp) val = C[a][b];
          S[r*17 + cq] = (r < 100 && cq < nbp) ? val : 0.0f;
        }
      }
    }
    {
      // panel rows k0..k0+15 owned by a==p: thread (ty,tx) holds C[p][b]
      float pv[4];
      #pragma unroll
      for (int b = 0; b < 4; ++b) pv[b] = 0.0f;
      #pragma unroll
      for (int a = 0; a < 7; ++a) {
        #pragma unroll
        for (int b = 0; b < 4; ++b) if (a == p) pv[b] = C[a][b];
      }
      #pragma unroll
      for (int b = 0; b < 4; ++b) Pr[ty*PRS + tx + 32*b] = pv[b];
    }
    __syncthreads();                                   // B1
    // ---- P2: wave 0 register-resident strip factorization (no pivoting)
    if (threadIdx.x < 64) {
      int lane = threadIdx.x;
      float P0[16], P1[16];
      #pragma unroll
      for (int c = 0; c < 16; ++c) {
        P0[c] = S[lane*17 + c];
        P1[c] = (lane + 64 < 112) ? S[(lane + 64)*17 + c] : 0.0f;
      }
      #pragma unroll
      for (int kk = 0; kk < 16; ++kk) {
        if (kk < nbp) {
          int kg = k0 + kk;
          int r1 = lane + 64;
          bool khigh = kg >= 64; int kl = kg & 63;
          float pivinv = 1.0f / flt_readlane(khigh ? P1[kk] : P0[kk], kl);
          float pr[16];
          #pragma unroll
          for (int c = 0; c < 16; ++c) {
            float pv = flt_readlane(khigh ? P1[c] : P0[c], kl);
            pr[c] = (c == kk) ? pivinv : pv*pivinv;
          }
          {
            float f = P0[kk];
            if (lane == kg) {
              #pragma unroll
              for (int c = 0; c < 16; ++c) P0[c] = pr[c];
            } else {
              #pragma unroll
              for (int c = 0; c < 16; ++c) P0[c] = ((c == kk) ? 0.0f : P0[c]) - f*pr[c];
            }
          }
          {
            float f = P1[kk];
            if (r1 == kg) {
              #pragma unroll
              for (int c = 0; c < 16; ++c) P1[c] = pr[c];
            } else {
              #pragma unroll
              for (int c = 0; c < 16; ++c) P1[c] = ((c == kk) ? 0.0f : P1[c]) - f*pr[c];
            }
          }
        }
      }
      #pragma unroll
      for (int c = 0; c < 16; ++c) {
        S[lane*17 + c] = P0[c];
        if (lane + 64 < 112) S[(lane + 64)*17 + c] = P1[c];
      }
    }
    __syncthreads();                                   // B2
    // ---- P3: mask C in REGISTERS, trailing rank-16 update, panel-col writeback
    #pragma unroll
    for (int a = 0; a < 7; ++a) {
      int r = ty + 16*a;
      bool prow_ = (r >= k0) && (r < k0 + 16);
      #pragma unroll
      for (int b = 0; b < 4; ++b) {
        int col = tx + 32*b;
        if (r >= 100 || (col >> 4) == p || prow_) C[a][b] = 0.0f;
      }
    }
    #pragma unroll 4
    for (int t = 0; t < 16; ++t) {
      bool tok = (t < nbp);
      float bt[4], sa[7];
      #pragma unroll
      for (int b = 0; b < 4; ++b) bt[b] = tok ? Pr[t*PRS + tx + 32*b] : 0.0f;
      #pragma unroll
      for (int a = 0; a < 7; ++a) sa[a] = S[(ty + 16*a)*17 + t];
      #pragma unroll
      for (int a = 0; a < 7; ++a)
        #pragma unroll
        for (int b = 0; b < 4; ++b) C[a][b] += sa[a]*bt[b];
    }
    #pragma unroll
    for (int a = 0; a < 7; ++a) {
      int r = ty + 16*a;
      #pragma unroll
      for (int b = 0; b < 4; ++b) {
        int col = tx + 32*b;
        if ((col >> 4) == p) C[a][b] = S[r*17 + (col & 15)];
      }
    }
    __syncthreads();                                   // B3 (WAR on S/Pr)
  }
  // Bm = Dv^{-1} - X
  #pragma unroll
  for (int a = 0; a < 7; ++a) {
    int r = ty + 16*a; if (r >= 100) continue;
    float dinv = 1.0f / svm[r];
    #pragma unroll
    for (int b = 0; b < 4; ++b) {
      int col = tx + 32*b; if (col >= 100) continue;
      float val = ((col == r) ? dinv : 0.0f) - C[a][b];
      out[OUT_B + (img*MM + r)*MM + col] = val;
    }
  }
}

extern "C" void kernel_launch(void* const* d_in, const int* in_sizes, int n_in,
                              void* d_out, int out_size, void* d_ws, size_t ws_size,
                              hipStream_t stream) {
  const float* pts = (const float*)d_in[0];
  float* out = (float*)d_out;
  char* ws = (char*)d_ws;
  double* vd  = (double*)(ws + OFF_VD);
  float* vmd = (float*)(ws + OFF_VM);
  float* ad  = (float*)(ws + OFF_AD);
  int* minds = (int*)(ws + OFF_MIND);

  hipLaunchKernelGGL(k_vpart, dim3(BB*64 + MU_VP/MU_PER), dim3(256), 0, stream, pts, vd, out);
  hipLaunchKernelGGL(k_select, dim3(BB + MU_SE/MU_PER), dim3(256), 0, stream, vd, out, minds, vmd, pts);
  hipLaunchKernelGGL(k_A, dim3(BB*56 + MU_KA/MU_PER), dim3(256), 0, stream, pts, minds, out, ad);
  hipLaunchKernelGGL(k_inv_m, dim3(BB + MU_IV/MU_PER), dim3(512), 0, stream, ad, vmd, pts, out);
}

// Round 17
// 186.431 us; speedup vs baseline: 1.1361x; 1.0112x over previous
//
#include <hip/hip_runtime.h>
#include <math.h>

#ifndef M_PI
#define M_PI 3.14159265358979323846
#endif

#define BB 8
#define NN 512
#define KK 64
#define GG 4096
#define MM 100

// ---------------- workspace layout (byte offsets) ----------------
// vd: FOUR fp64 partial quarters (split-K x4); ad: TWO fp32 partial halves
#define SZ_VD    (BB*GG*8u*4u)
#define OFF_VD   0u
#define SZ_VM    (BB*MM*4u)
#define OFF_VM   (OFF_VD + SZ_VD)
#define SZ_AD    (BB*MM*MM*4u*2u)
#define OFF_AD   (OFF_VM + SZ_VM)
#define OFF_MIND (OFF_AD + SZ_AD)

// ---------------- output layout (float element offsets) ----------------
#define OUT_M  0
#define OUT_V  (BB*NN*GG)               // 16,777,216
#define OUT_A  (OUT_V + BB*GG)          // 16,809,984
#define OUT_B  (OUT_A + BB*MM*MM)      // 16,889,984
#define OUT_MI (OUT_B + BB*MM*MM)      // 16,969,984

// ---------------- m-unit allocation across dispatches ----------------
// r17: rebalanced toward the longest dispatch (inv). vpart is short now.
#define MU_PER 8
#define MU_VP 2048            // with k_vpart   -> 256 m-blocks
#define MU_SE 1024            // with k_select  -> 128 m-blocks
#define MU_KA 2048            // with k_A       -> 256 m-blocks
#define MU_IV 11264           // with k_inv_m   -> 1408 m-blocks

__device__ __forceinline__ void m_units(const float* __restrict__ pts,
                                        float* __restrict__ out, int u0, int cnt) {
  const float CM = (float)(1.0/(2.0*M_PI*128.0));
  for (int k = 0; k < cnt; ++k) {
    int u = u0 + k;
    int t = u*256 + (int)threadIdx.x;
    int e = t << 2;
    int img = e >> 21;
    int rem = e & ((1 << 21) - 1);
    int n = rem >> 12;
    int g = rem & 4095;
    int iy = g >> 6, ix = g & 63;       // e%4==0 -> ix%4==0
    float x = pts[(img*NN + n)*2 + 0];
    float y = pts[(img*NN + n)*2 + 1];
    float dy = y - (8.0f*iy + 4.0f);
    float ey = __expf(dy*dy*(-0.5f/128.0f));
    float4 r;
    float dx0 = x - (8.0f*ix + 4.0f);
    float dx1 = x - (8.0f*(ix+1) + 4.0f);
    float dx2 = x - (8.0f*(ix+2) + 4.0f);
    float dx3 = x - (8.0f*(ix+3) + 4.0f);
    r.x = ey*__expf(dx0*dx0*(-0.5f/128.0f))*CM;
    r.y = ey*__expf(dx1*dx1*(-0.5f/128.0f))*CM;
    r.z = ey*__expf(dx2*dx2*(-0.5f/128.0f))*CM;
    r.w = ey*__expf(dx3*dx3*(-0.5f/128.0f))*CM;
    *reinterpret_cast<float4*>(&out[OUT_M + e]) = r;
  }
}

// 512-thread variant: cnt units, 2 units per pass (512 thr x float4 = 2 units)
__device__ __forceinline__ void m_units512(const float* __restrict__ pts,
                                           float* __restrict__ out, int u0, int cnt) {
  const float CM = (float)(1.0/(2.0*M_PI*128.0));
  for (int k = 0; k < cnt/2; ++k) {
    int t = u0*256 + k*512 + (int)threadIdx.x;
    int e = t << 2;
    int img = e >> 21;
    int rem = e & ((1 << 21) - 1);
    int n = rem >> 12;
    int g = rem & 4095;
    int iy = g >> 6, ix = g & 63;
    float x = pts[(img*NN + n)*2 + 0];
    float y = pts[(img*NN + n)*2 + 1];
    float dy = y - (8.0f*iy + 4.0f);
    float ey = __expf(dy*dy*(-0.5f/128.0f));
    float4 r;
    float dx0 = x - (8.0f*ix + 4.0f);
    float dx1 = x - (8.0f*(ix+1) + 4.0f);
    float dx2 = x - (8.0f*(ix+2) + 4.0f);
    float dx3 = x - (8.0f*(ix+3) + 4.0f);
    r.x = ey*__expf(dx0*dx0*(-0.5f/128.0f))*CM;
    r.y = ey*__expf(dx1*dx1*(-0.5f/128.0f))*CM;
    r.z = ey*__expf(dx2*dx2*(-0.5f/128.0f))*CM;
    r.w = ey*__expf(dx3*dx3*(-0.5f/128.0f))*CM;
    *reinterpret_cast<float4*>(&out[OUT_M + e]) = r;
  }
}

__device__ __forceinline__ float flt_readlane(float v, int l) {
  return __int_as_float(__builtin_amdgcn_readlane(__float_as_int(v), l));
}

// ============ K2: v — SPLIT-K x4 + recurrence exp tables + double2 LDS reads ============
__global__ __launch_bounds__(256) void k_vpart(const float* __restrict__ pts,
                                               double* __restrict__ vd,
                                               float* __restrict__ out) {
  __shared__ double sEy2[16][66], sEy3[16][66], sEx2[16][66], sEx3[16][66];
  __shared__ float px[128], py[128];
  int bid = blockIdx.x;                 // (img*16+tile)*4+quarter  |  m blocks
  if (bid >= BB*64) { m_units(pts, out, (bid - BB*64)*MU_PER, MU_PER); return; }
  int quarter = bid & 3;
  int rem = bid >> 2;
  int tile = rem & 15;
  int img = rem >> 4;
  int iy0 = (tile >> 2) << 4;
  int ix0 = (tile & 3) << 4;
  int tx = threadIdx.x & 15, ty = threadIdx.x >> 4;
  int n = threadIdx.x & 63;             // point-in-chunk this thread fills
  int tbl = threadIdx.x >> 6;           // wave -> table (wave-uniform)
  if (threadIdx.x < 128) {
    px[threadIdx.x] = pts[(img*NN + quarter*128 + threadIdx.x)*2 + 0];
    py[threadIdx.x] = pts[(img*NN + quarter*128 + threadIdx.x)*2 + 1];
  }
  const double alpha = (tbl & 1) ? (1.0/128.0) : (0.5/96.0);
  const double Q = exp(-128.0*alpha);   // exp(-2/3) or exp(-1), hoisted
  const int base = (tbl >= 2) ? ix0 : iy0;
  double* dst = (tbl == 0) ? &sEy2[0][0] : (tbl == 1) ? &sEy3[0][0]
              : (tbl == 2) ? &sEx2[0][0] : &sEx3[0][0];
  double aV = 0.0, aM = 0.0;
  for (int kc = 0; kc < 2; ++kc) {
    int nbl = kc << 6;
    __syncthreads();                    // WAR on LDS (and px/py ready on kc=0)
    {
      int nn = nbl + n;
      double coord = (tbl >= 2) ? (double)px[nn] : (double)py[nn];
      double d0 = coord - (8.0*base + 4.0);
      double E = exp(-alpha*d0*d0);     // row 0 value
      double R = exp(alpha*(16.0*d0 - 64.0));
      #pragma unroll
      for (int row = 0; row < 16; ++row) {
        dst[row*66 + n] = E;
        E *= R; R *= Q;
      }
    }
    __syncthreads();
    #pragma unroll 8
    for (int n2 = 0; n2 < 64; n2 += 2) {
      double2 y2 = *reinterpret_cast<const double2*>(&sEy2[ty][n2]);
      double2 x2 = *reinterpret_cast<const double2*>(&sEx2[tx][n2]);
      double2 y3 = *reinterpret_cast<const double2*>(&sEy3[ty][n2]);
      double2 x3 = *reinterpret_cast<const double2*>(&sEx3[tx][n2]);
      aV += y2.x*x2.x; aV += y2.y*x2.y;  // same sequential order as scalar loop
      aM += y3.x*x3.x; aM += y3.y*x3.y;
    }
  }
  const double CTV = 1.0/((2.0*M_PI*96.0)*(2.0*M_PI*128.0));
  const double CM2 = 1.0/((2.0*M_PI*128.0)*(2.0*M_PI*128.0));
  vd[quarter*(BB*GG) + img*GG + (iy0 + ty)*KK + ix0 + tx] = CTV*aV - CM2*aM;
}

// ---------------- single-wave bitonic sort of 128 ints (2 elems/lane) ----------------
__device__ __forceinline__ void wave_sort128(int* a) {
  int L = (int)(threadIdx.x & 63);
  int e0 = a[2*L], e1 = a[2*L + 1];
  for (int kk = 2; kk <= 128; kk <<= 1) {
    for (int jj = kk >> 1; jj >= 2; jj >>= 1) {
      int pl = jj >> 1;
      int o0 = __shfl_xor(e0, pl);
      int o1 = __shfl_xor(e1, pl);
      bool upper = (L & pl) != 0;
      bool up = ((2*L) & kk) == 0;
      if (up != upper) { e0 = min(e0, o0); e1 = min(e1, o1); }
      else             { e0 = max(e0, o0); e1 = max(e1, o1); }
    }
    bool up = ((2*L) & kk) == 0;
    int lo = min(e0, e1), hi = max(e0, e1);
    e0 = up ? lo : hi; e1 = up ? hi : lo;
  }
  a[2*L] = e0; a[2*L + 1] = e1;
}

// ============ K3: top-100 select — ONCE per image (8 blocks) + m blocks ============
__global__ __launch_bounds__(256) void k_select(const double* __restrict__ vd,
                                               float* __restrict__ out,
                                               int* __restrict__ minds,
                                               float* __restrict__ vm,
                                               const float* __restrict__ pts) {
  __shared__ unsigned int ku[GG];              // 16 KB fp32 sortable keys
  __shared__ unsigned int hist[32][257];       // 32 copies, bank-spread
  __shared__ unsigned int wq[4];
  __shared__ unsigned int sPref, sMask;
  __shared__ unsigned int sRem, sPickB, sPickRem, sCGt, sCEq;
  __shared__ int tie[128];
  __shared__ int selFinal[128];
  int bid = blockIdx.x;
  if (bid >= BB) { m_units(pts, out, MU_VP + (bid - BB)*MU_PER, MU_PER); return; }
  int img = bid;
  int tid = threadIdx.x;
  int wv = tid >> 6;
  int lane = tid & 63;
  int hc = tid >> 3;                    // histogram copy (8 lanes per copy)

  for (int t = 0; t < 16; ++t) {
    int g = t*256 + tid;
    // deterministic fixed-order sum of the four split-K partials
    float v = (float)(((vd[img*GG + g] + vd[BB*GG + img*GG + g])
                     + vd[2*BB*GG + img*GG + g]) + vd[3*BB*GG + img*GG + g]);
    out[OUT_V + img*GG + g] = fmaxf(v, 1e-6f);
    int w = __float_as_int(v);
    ku[g] = (w < 0) ? ~(unsigned)w : ((unsigned)w | 0x80000000u);
  }
  if (tid == 0) {
    sRem = 100; sPref = 0u; sMask = 0u;
    sCGt = 0; sCEq = 0;
  }
  // ---- 4 radix passes, MSB first ----
  for (int shift = 24; shift >= 0; shift -= 8) {
    for (int s = tid; s < 32*257; s += 256) (&hist[0][0])[s] = 0;
    __syncthreads();                    // ku/state ready, hist zeroed
    unsigned mask = sMask, pref = sPref;
    for (int t = 0; t < 16; ++t) {
      unsigned k = ku[t*256 + tid];
      if ((k & mask) == pref)
        atomicAdd(&hist[hc][(k >> shift) & 255u], 1u);
    }
    __syncthreads();
    unsigned tot = 0;
    #pragma unroll
    for (int c = 0; c < 32; ++c) tot += hist[c][tid];  // banks spread: conflict-free
    // wave-level inclusive SUFFIX scan over the 64 bins this wave owns
    unsigned val = tot;
    #pragma unroll
    for (int off = 1; off < 64; off <<= 1) {
      unsigned o = (unsigned)__shfl_down((int)val, off);
      if (lane + off < 64) val += o;
    }
    if (lane == 0) wq[wv] = val;        // whole-wave total
    __syncthreads();
    unsigned suf = val;                 // + totals of higher waves (higher digits)
    for (int w2 = wv + 1; w2 < 4; ++w2) suf += wq[w2];
    unsigned rem = sRem;
    unsigned sgt = suf - tot;           // count with digit strictly greater
    if (suf >= rem && sgt < rem) { sPickB = (unsigned)tid; sPickRem = rem - sgt; }
    __syncthreads();
    if (tid == 0) {
      sPref |= sPickB << shift;
      sMask |= 255u << shift;
      sRem   = sPickRem;
    }
    __syncthreads();
  }
  // ---- collect: all k > T, plus r smallest-index ties (k == T) ----
  unsigned T = sPref;                   // exact 100th-largest fp32 key
  for (int t = 0; t < 16; ++t) {
    int g = t*256 + tid;
    unsigned k = ku[g];
    if (k > T) {
      unsigned p = atomicAdd(&sCGt, 1u);        // p <= 98 always
      selFinal[p] = g;
    } else if (k == T) {
      unsigned p = atomicAdd(&sCEq, 1u);
      if (p < 128) tie[p] = g;          // >128 exact-equal boundary: pathological
    }
  }
  __syncthreads();
  unsigned cgt = sCGt, ceq = sCEq, r = sRem;
  if (tid < 128 && tid >= (int)((ceq < 128u) ? ceq : 128u)) tie[tid] = 0x7fffffff;
  __syncthreads();
  if (tid < 64) wave_sort128(tie);               // ties ascending by index
  __syncthreads();
  if (tid < (int)r) selFinal[cgt + tid] = tie[tid];
  if (tid >= MM && tid < 128) selFinal[tid] = 0x7fffffff;
  __syncthreads();
  if (tid < 64) wave_sort128(selFinal);          // final Minds ascending
  __syncthreads();
  if (tid < MM) {
    int mi = selFinal[tid];
    minds[img*MM + tid] = mi;
    out[OUT_MI + img*MM + tid] = (float)mi;      // whole out buffer is float32
    float vsel = (float)(((vd[img*GG + mi] + vd[BB*GG + img*GG + mi])
                        + vd[2*BB*GG + img*GG + mi]) + vd[3*BB*GG + img*GG + mi]);
    vm[img*MM + tid] = fmaxf(vsel, 1e-6f) + 1e-10f;  // ref fp32 semantics
  }
}

// ============ K4: A assembly — SPLIT-N x2, minds from ws + m blocks ============
__global__ __launch_bounds__(256) void k_A(const float* __restrict__ pts,
                                           const int* __restrict__ minds,
                                           float* __restrict__ out,
                                           float* __restrict__ ad) {
  __shared__ float sxi[16][130], syi[16][130], sti[16][130];
  __shared__ float sxj[16][130], syj[16][130], stj[16][130];
  __shared__ float px[256], py[256];
  __shared__ float cxi[16], cyi[16], cxj[16], cyj[16];
  int bid = blockIdx.x;                 // img*56 + tile*2 + half  |  m blocks
  if (bid >= BB*56) { m_units(pts, out, MU_VP + MU_SE + (bid - BB*56)*MU_PER, MU_PER); return; }
  int img = bid / 56;
  int rem56 = bid - img*56;
  int tile = rem56 >> 1;
  int half = rem56 & 1;
  int tid = threadIdx.x;
  int it = 0, trem = tile;
  while (trem >= 7 - it) { trem -= 7 - it; ++it; }
  int jt = it + trem;
  int i0 = it*16, j0 = jt*16;
  int tj = tid & 15, ti = tid >> 4;
  int i = i0 + ti, j = j0 + tj;
  const float CM = (float)(1.0/(2.0*M_PI*128.0));
  const float C1 = (float)(1.0/(2.0*M_PI*128.0));   // g1 scale (2*pi*2*sigma2)
  const float C2 = (float)(1.0/(2.0*M_PI*96.0));    // h scale (2*pi*s2)
  if (tid < 256) {                                  // this block's 256 points
    px[tid] = pts[(img*NN + half*256 + tid)*2 + 0];
    py[tid] = pts[(img*NN + half*256 + tid)*2 + 1];
  }
  if (tid < 16) {
    int gi = i0 + tid; if (gi > 99) gi = 99;
    int mi = minds[img*MM + gi];
    cxi[tid] = 8.0f*(mi & 63) + 4.0f;
    cyi[tid] = 8.0f*(mi >> 6) + 4.0f;
  } else if (tid < 32) {
    int rr = tid - 16;
    int gj = j0 + rr; if (gj > 99) gj = 99;
    int mj = minds[img*MM + gj];
    cxj[rr] = 8.0f*(mj & 63) + 4.0f;
    cyj[rr] = 8.0f*(mj >> 6) + 4.0f;
  }
  float aV = 0.0f, aM = 0.0f;
  for (int c2 = 0; c2 < 256; c2 += 128) {
    __syncthreads();
    for (int s = tid; s < 16*128; s += 256) {
      int row = s >> 7, n = s & 127;
      float x = px[c2 + n], y = py[c2 + n];
      float fxi = x - cxi[row], fyi = y - cyi[row];
      sxi[row][n] = fxi; syi[row][n] = fyi;
      sti[row][n] = __expf((fxi*fxi + fyi*fyi)*(-0.5f/128.0f))*CM;
      float fxj = x - cxj[row], fyj = y - cyj[row];
      sxj[row][n] = fxj; syj[row][n] = fyj;
      stj[row][n] = __expf((fxj*fxj + fyj*fyj)*(-0.5f/128.0f))*CM;
    }
    __syncthreads();
    #pragma unroll 4
    for (int n = 0; n < 128; ++n) {
      float xi = sxi[ti][n], yi = syi[ti][n], tii = sti[ti][n];
      float xj = sxj[tj][n], yj = syj[tj][n], tjj = stj[tj][n];
      float ddx = xj - xi, ddy = yj - yi;
      float df = ddx*ddx + ddy*ddy;
      float sx = 0.5f*(xi + xj), sy = 0.5f*(yi + yj);
      float af = sx*sx + sy*sy;
      float g1 = __expf(df*(-0.5f/128.0f))*C1;
      float h  = __expf(af*(-0.5f/96.0f))*C2;
      aV += g1 + g1*h;
      aM += tii*tjj;
    }
  }
  if (i < 100 && j < 100) {
    float val = (i == j) ? 1e-10f : (float)((double)aV - (double)aM);
    ad[((half*BB + img)*MM + i)*MM + j] = val;
    if (it != jt) {                     // mirror (diag tiles cover both in-tile)
      ad[((half*BB + img)*MM + j)*MM + i] = val;
    }
  }
}

// ============ K5: FP32 GJ inversion, 512-THREAD blocks; sums ad2 partials, emits OUT_A ============
// r17: P2 pivot reciprocal via raw v_rcp_f32 (drops NR-refined divide from the
// 112-step serial chain; ~1 ulp/step, absmax headroom 512 vs 8110 threshold).
#define PRS 130
__global__ __launch_bounds__(512)
void k_inv_m(const float* __restrict__ ad,
             const float* __restrict__ vm,
             const float* __restrict__ pts,
             float* __restrict__ out) {
  __shared__ float S[128*17];           //  8,704 B
  __shared__ float Pr[16*PRS];          //  8,320 B
  __shared__ float svm[112];            //    448 B  -> total ~17.5 KB
  if (blockIdx.x >= BB) {
    m_units512(pts, out, MU_VP + MU_SE + MU_KA + ((int)blockIdx.x - BB)*MU_PER, MU_PER);
    return;
  }
  int img = blockIdx.x;
  int tx = threadIdx.x & 31, ty = threadIdx.x >> 5;   // ty in [0,16), tx in [0,32)
  float C[7][4];
  if (threadIdx.x < 100) svm[threadIdx.x] = vm[img*MM + threadIdx.x];
  // init C = (ad2[0]+ad2[1]) + diag(vM); also emit OUT_A (sum; diag 1e-10)
  #pragma unroll
  for (int a = 0; a < 7; ++a) {
    int r = ty + 16*a;
    #pragma unroll
    for (int b = 0; b < 4; ++b) {
      int col = tx + 32*b;
      float v2 = 0.0f;
      if (r < 100 && col < 100) {
        if (r == col) {
          v2 = 1e-10f + vm[img*MM + r];
          out[OUT_A + (img*MM + r)*MM + col] = 1e-10f;
        } else {
          float s = ad[(img*MM + r)*MM + col] + ad[((BB + img)*MM + r)*MM + col];
          v2 = s;
          out[OUT_A + (img*MM + r)*MM + col] = s;
        }
      }
      C[a][b] = v2;
    }
  }
  for (int p = 0; p < 7; ++p) {
    int k0 = p*16;
    int nbp = (p == 6) ? 4 : 16;
    // ---- P1: stage panel-col strip S + panel rows Pr (phase-start values)
    {
      int bp = p >> 1;                   // chunk containing panel p
      bool mine = ((tx >> 4) == (p & 1));// my half of that chunk
      int cq = tx & 15;                  // panel-local column
      #pragma unroll
      for (int a = 0; a < 7; ++a) {
        int r = ty + 16*a;
        if (mine) {
          float val = 0.0f;
          #pragma unroll
          for (int b = 0; b < 4; ++b) if (b == bp) val = C[a][b];
          S[r*17 + cq] = (r < 100 && cq < nbp) ? val : 0.0f;
        }
      }
    }
    {
      // panel rows k0..k0+15 owned by a==p: thread (ty,tx) holds C[p][b]
      float pv[4];
      #pragma unroll
      for (int b = 0; b < 4; ++b) pv[b] = 0.0f;
      #pragma unroll
      for (int a = 0; a < 7; ++a) {
        #pragma unroll
        for (int b = 0; b < 4; ++b) if (a == p) pv[b] = C[a][b];
      }
      #pragma unroll
      for (int b = 0; b < 4; ++b) Pr[ty*PRS + tx + 32*b] = pv[b];
    }
    __syncthreads();                                   // B1
    // ---- P2: wave 0 register-resident strip factorization (no pivoting)
    if (threadIdx.x < 64) {
      int lane = threadIdx.x;
      float P0[16], P1[16];
      #pragma unroll
      for (int c = 0; c < 16; ++c) {
        P0[c] = S[lane*17 + c];
        P1[c] = (lane + 64 < 112) ? S[(lane + 64)*17 + c] : 0.0f;
      }
      #pragma unroll
      for (int kk = 0; kk < 16; ++kk) {
        if (kk < nbp) {
          int kg = k0 + kk;
          int r1 = lane + 64;
          bool khigh = kg >= 64; int kl = kg & 63;
          float pivinv = __builtin_amdgcn_rcpf(flt_readlane(khigh ? P1[kk] : P0[kk], kl));
          float pr[16];
          #pragma unroll
          for (int c = 0; c < 16; ++c) {
            float pv = flt_readlane(khigh ? P1[c] : P0[c], kl);
            pr[c] = (c == kk) ? pivinv : pv*pivinv;
          }
          {
            float f = P0[kk];
            if (lane == kg) {
              #pragma unroll
              for (int c = 0; c < 16; ++c) P0[c] = pr[c];
            } else {
              #pragma unroll
              for (int c = 0; c < 16; ++c) P0[c] = ((c == kk) ? 0.0f : P0[c]) - f*pr[c];
            }
          }
          {
            float f = P1[kk];
            if (r1 == kg) {
              #pragma unroll
              for (int c = 0; c < 16; ++c) P1[c] = pr[c];
            } else {
              #pragma unroll
              for (int c = 0; c < 16; ++c) P1[c] = ((c == kk) ? 0.0f : P1[c]) - f*pr[c];
            }
          }
        }
      }
      #pragma unroll
      for (int c = 0; c < 16; ++c) {
        S[lane*17 + c] = P0[c];
        if (lane + 64 < 112) S[(lane + 64)*17 + c] = P1[c];
      }
    }
    __syncthreads();                                   // B2
    // ---- P3: mask C in REGISTERS, trailing rank-16 update, panel-col writeback
    #pragma unroll
    for (int a = 0; a < 7; ++a) {
      int r = ty + 16*a;
      bool prow_ = (r >= k0) && (r < k0 + 16);
      #pragma unroll
      for (int b = 0; b < 4; ++b) {
        int col = tx + 32*b;
        if (r >= 100 || (col >> 4) == p || prow_) C[a][b] = 0.0f;
      }
    }
    #pragma unroll 4
    for (int t = 0; t < 16; ++t) {
      bool tok = (t < nbp);
      float bt[4], sa[7];
      #pragma unroll
      for (int b = 0; b < 4; ++b) bt[b] = tok ? Pr[t*PRS + tx + 32*b] : 0.0f;
      #pragma unroll
      for (int a = 0; a < 7; ++a) sa[a] = S[(ty + 16*a)*17 + t];
      #pragma unroll
      for (int a = 0; a < 7; ++a)
        #pragma unroll
        for (int b = 0; b < 4; ++b) C[a][b] += sa[a]*bt[b];
    }
    #pragma unroll
    for (int a = 0; a < 7; ++a) {
      int r = ty + 16*a;
      #pragma unroll
      for (int b = 0; b < 4; ++b) {
        int col = tx + 32*b;
        if ((col >> 4) == p) C[a][b] = S[r*17 + (col & 15)];
      }
    }
    __syncthreads();                                   // B3 (WAR on S/Pr)
  }
  // Bm = Dv^{-1} - X
  #pragma unroll
  for (int a = 0; a < 7; ++a) {
    int r = ty + 16*a; if (r >= 100) continue;
    float dinv = 1.0f / svm[r];
    #pragma unroll
    for (int b = 0; b < 4; ++b) {
      int col = tx + 32*b; if (col >= 100) continue;
      float val = ((col == r) ? dinv : 0.0f) - C[a][b];
      out[OUT_B + (img*MM + r)*MM + col] = val;
    }
  }
}

extern "C" void kernel_launch(void* const* d_in, const int* in_sizes, int n_in,
                              void* d_out, int out_size, void* d_ws, size_t ws_size,
                              hipStream_t stream) {
  const float* pts = (const float*)d_in[0];
  float* out = (float*)d_out;
  char* ws = (char*)d_ws;
  double* vd  = (double*)(ws + OFF_VD);
  float* vmd = (float*)(ws + OFF_VM);
  float* ad  = (float*)(ws + OFF_AD);
  int* minds = (int*)(ws + OFF_MIND);

  hipLaunchKernelGGL(k_vpart, dim3(BB*64 + MU_VP/MU_PER), dim3(256), 0, stream, pts, vd, out);
  hipLaunchKernelGGL(k_select, dim3(BB + MU_SE/MU_PER), dim3(256), 0, stream, vd, out, minds, vmd, pts);
  hipLaunchKernelGGL(k_A, dim3(BB*56 + MU_KA/MU_PER), dim3(256), 0, stream, pts, minds, out, ad);
  hipLaunchKernelGGL(k_inv_m, dim3(BB + MU_IV/MU_PER), dim3(512), 0, stream, ad, vmd, pts, out);
}